// Round 5
// baseline (765.777 us; speedup 1.0000x reference)
//
#include <hip/hip_runtime.h>
#include <hip/hip_bf16.h>
#include <math.h>

// STAttentionBlock  N=32 C=64 T=400 V=27 S=2 IC=16 — f32 I/O.
// Round 8: kill the AGPR/VGPR split by construction — stage1/stage2 folds
// restructured into two half-passes with acc[32] live (mm recomputed per
// half; fold-per-pair immediately, no mp[] array). att_s stride 17 to fix
// 13-way bank conflict on a4 loads. Full unroll where private arrays are
// indexed. k_scores unchanged from round 7.

typedef __hip_bfloat16 bf16;
typedef unsigned short u16t;
typedef unsigned int u32t;

#define NN 32
#define CH 64
#define TT 400
#define VV 27
#define PIX 10800            // T*V
#define NSUV (32*2*27*27)    // 46656
#define XTOT (NN*CH*PIX)     // 22118400

#define TB1 9                // t per block, stage1
#define PXS1 (TB1*27)        // 243 active pixel lanes
#define NT1 45
#define TB2 9
#define PXS2 (TB2*27)
#define NT2 45
#define TBS 9                // t per block, scores
#define NTS 45

__device__ __forceinline__ float lrelu(float x) { return x >= 0.f ? x : 0.1f * x; }
__device__ __forceinline__ uint4 ld4u(const u32t* p) { return *reinterpret_cast<const uint4*>(p); }
__device__ __forceinline__ uint2 ld2u(const u32t* p) { return *reinterpret_cast<const uint2*>(p); }

// packed bf16 helpers
__device__ __forceinline__ u16t f2bf(float f) {
    return __bfloat16_as_ushort(__float2bfloat16(f));
}
__device__ __forceinline__ u32t packbf(float lo, float hi) {
    return ((u32t)f2bf(hi) << 16) | (u32t)f2bf(lo);
}
__device__ __forceinline__ float bf2f(u16t u) {
    return __uint_as_float(((u32t)u) << 16);
}
__device__ __forceinline__ u32t cvtpk(float lo, float hi) {
    u32t r;
    asm("v_cvt_pk_bf16_f32 %0, %1, %2" : "=v"(r) : "v"(lo), "v"(hi));
    return r;
}
// c += a.lo*b.lo + a.hi*b.hi  (bf16 pairs, f32 accum)
__device__ __forceinline__ void dot2v(float& c, u32t a, u32t b) {
    asm("v_dot2_f32_bf16 %0, %1, %2, %0" : "+v"(c) : "v"(a), "v"(b));
}
__device__ __forceinline__ void dot2s(float& c, u32t a_sgpr, u32t b) {
    asm("v_dot2_f32_bf16 %0, %1, %2, %0" : "+v"(c) : "s"(a_sgpr), "v"(b));
}

// ---------------------------------------------------------------------------
// k_prep: BN-folded, transposed, bf16x2-packed weights + packed w_in.
//   wfopk[j2*64+o]           j2<64   conv_outs (K=128 pairs)
//   wffpk[c2*64+o]           c2<32   ff        (K=64 pairs)
//   wt2pk[(kt*32+c2)*64+o]           tconv     (K=192 as 3x32 pairs)
//   wqkpk[(sq*16+c)*32+cc2]  sq=s*2+qk, row = qk*32+s*16+c
//   b*[o] = b[o]*inv + beta
// ---------------------------------------------------------------------------
__global__ void k_prep(
    const float* __restrict__ w_outs, const float* __restrict__ b_outs,
    const float* __restrict__ go, const float* __restrict__ bo,
    const float* __restrict__ mo, const float* __restrict__ vo,
    const float* __restrict__ w_ff, const float* __restrict__ b_ff,
    const float* __restrict__ gf, const float* __restrict__ bf,
    const float* __restrict__ mf, const float* __restrict__ vf,
    const float* __restrict__ w_t, const float* __restrict__ b_t,
    const float* __restrict__ gt, const float* __restrict__ btb,
    const float* __restrict__ mt, const float* __restrict__ vt,
    const float* __restrict__ w_in,
    u32t* __restrict__ wfopk, float* __restrict__ bfo,
    u32t* __restrict__ wffpk, float* __restrict__ bff,
    u32t* __restrict__ wt2pk, float* __restrict__ bft,
    u32t* __restrict__ wqkpk)
{
    const int total = 4096 + 2048 + 6144 + 192 + 2048;
    for (int idx = blockIdx.x * 256 + threadIdx.x; idx < total; idx += gridDim.x * 256) {
        if (idx < 4096) {
            int o = idx & 63, j2 = idx >> 6;
            float inv = go[o] * rsqrtf(vo[o] + 1e-5f);
            wfopk[idx] = packbf(w_outs[o * 128 + 2 * j2] * inv,
                                w_outs[o * 128 + 2 * j2 + 1] * inv);
        } else if (idx < 6144) {
            int r = idx - 4096; int o = r & 63, c2 = r >> 6;
            float inv = gf[o] * rsqrtf(vf[o] + 1e-5f);
            wffpk[r] = packbf(w_ff[o * 64 + 2 * c2] * inv,
                              w_ff[o * 64 + 2 * c2 + 1] * inv);
        } else if (idx < 12288) {
            int r = idx - 6144; int o = r & 63, q = r >> 6;   // q < 96
            int kt = q >> 5, c2 = q & 31;
            float inv = gt[o] * rsqrtf(vt[o] + 1e-5f);
            wt2pk[r] = packbf(w_t[o * 192 + (2 * c2) * 3 + kt] * inv,
                              w_t[o * 192 + (2 * c2 + 1) * 3 + kt] * inv);
        } else if (idx < 12480) {
            int r = idx - 12288; int o = r & 63, which = r >> 6;
            if (which == 0) {
                float inv = go[o] * rsqrtf(vo[o] + 1e-5f);
                bfo[o] = b_outs[o] * inv + bo[o] - mo[o] * inv;
            } else if (which == 1) {
                float inv = gf[o] * rsqrtf(vf[o] + 1e-5f);
                bff[o] = b_ff[o] * inv + bf[o] - mf[o] * inv;
            } else {
                float inv = gt[o] * rsqrtf(vt[o] + 1e-5f);
                bft[o] = b_t[o] * inv + btb[o] - mt[o] * inv;
            }
        } else {
            int i = idx - 12480;                 // i < 2048
            int cc2 = i & 31, c = (i >> 5) & 15, sq = i >> 9;
            int s = sq >> 1, qk = sq & 1;
            int row = qk * 32 + s * 16 + c;
            wqkpk[i] = packbf(w_in[row * 64 + 2 * cc2], w_in[row * 64 + 2 * cc2 + 1]);
        }
    }
}

// ---------------------------------------------------------------------------
// k_pbias: pb[s*2+qk][c][u28] = b_in + sum_cc w_in * pe[cc][u]  (PE absorbed)
// ---------------------------------------------------------------------------
__global__ __launch_bounds__(256) void k_pbias(
    const float* __restrict__ w_in, const float* __restrict__ b_in,
    float* __restrict__ pb)
{
    __shared__ float pe[64 * 27];
    const int tid = threadIdx.x;
    for (int idx = tid; idx < 1728; idx += 256) {
        int c = idx / 27, u = idx % 27;
        float div = expf(-0.28782313662425575f * (float)(c >> 1));
        float ang = div * (float)u;
        pe[idx] = (c & 1) ? cosf(ang) : sinf(ang);
    }
    __syncthreads();
    for (int idx = tid; idx < 1792; idx += 256) {
        int u = idx % 28, r = idx / 28;
        int c = r % 16, sq = r / 16;
        if (u >= 27) { pb[idx] = 0.f; continue; }
        int s = sq >> 1, qk = sq & 1;
        int row = qk * 32 + s * 16 + c;
        float acc = b_in[row];
        for (int cc = 0; cc < 64; ++cc) acc += w_in[row * 64 + cc] * pe[cc * 27 + u];
        pb[idx] = acc;
    }
}

// ---------------------------------------------------------------------------
// k_scores: grid (45 tchunks, 2 s, 32 n). Lane = pixel (tt,u).
// ---------------------------------------------------------------------------
__global__ __launch_bounds__(256, 4) void k_scores(
    const float* __restrict__ x, const u32t* __restrict__ wqkpk,
    const float* __restrict__ pb, float* __restrict__ scores)
{
    const int tid = threadIdx.x;
    const int s = blockIdx.y, n = blockIdx.z;
    const int t0 = blockIdx.x * TBS;

    __shared__ u32t qlds[TBS * 27 * 10];
    __shared__ u32t klds[TBS * 27 * 10];

    const int pcl = tid < 243 ? tid : 242;
    const int tt = pcl / 27, u = pcl - tt * 27;
    const int t = t0 + tt;
    const bool valid = (tid < 243) && (t < TT);

    // ---- load + pack x channels for this pixel ----
    u32t xp[32];
    const float* xb = x + (size_t)n * 64 * PIX + (size_t)(t < TT ? t : 0) * 27 + u;
    #pragma unroll
    for (int c2 = 0; c2 < 32; ++c2) {
        float v0 = xb[(size_t)(2 * c2) * PIX];
        float v1 = xb[(size_t)(2 * c2 + 1) * PIX];
        xp[c2] = cvtpk(v0, v1);
    }

    // ---- proj ----
    const float* pbq = pb + ((s * 2 + 0) * 16) * 28 + u;
    const float* pbk = pb + ((s * 2 + 1) * 16) * 28 + u;
    const u32t* wq = wqkpk + (s * 2 + 0) * 16 * 32;
    const u32t* wk = wqkpk + (s * 2 + 1) * 16 * 32;
    float qr[16], kr[16];
    #pragma unroll
    for (int c = 0; c < 16; ++c) { qr[c] = pbq[c * 28]; kr[c] = pbk[c * 28]; }
    #pragma unroll
    for (int c = 0; c < 16; ++c) {
        const u32t* wr = wq + c * 32;
        #pragma unroll
        for (int c2 = 0; c2 < 32; ++c2) dot2s(qr[c], wr[c2], xp[c2]);
    }
    #pragma unroll
    for (int c = 0; c < 16; ++c) {
        const u32t* wr = wk + c * 32;
        #pragma unroll
        for (int c2 = 0; c2 < 32; ++c2) dot2s(kr[c], wr[c2], xp[c2]);
    }

    if (tid < 243) {
        #pragma unroll
        for (int c2 = 0; c2 < 8; ++c2) {
            qlds[(tt * 27 + u) * 10 + c2] = valid ? cvtpk(qr[2 * c2], qr[2 * c2 + 1]) : 0u;
            klds[(tt * 27 + u) * 10 + c2] = valid ? cvtpk(kr[2 * c2], kr[2 * c2 + 1]) : 0u;
        }
    }
    __syncthreads();

    // ---- score stage ----
    const int sid = tid < 243 ? tid : 242;
    const int ug = sid / 9, vg = sid % 9;
    const int v0 = vg * 3;
    float sc0 = 0.f, sc1 = 0.f, sc2 = 0.f;
    for (int t2 = 0; t2 < TBS; ++t2) {
        const u32t* qrow = qlds + (t2 * 27 + ug) * 10;
        const u32t* k0 = klds + (t2 * 27 + v0) * 10;
        #pragma unroll
        for (int c4 = 0; c4 < 4; ++c4) {
            uint2 qp = ld2u(qrow + c4 * 2);
            uint2 ka = ld2u(k0 + c4 * 2);
            uint2 kb = ld2u(k0 + 10 + c4 * 2);
            uint2 kc = ld2u(k0 + 20 + c4 * 2);
            dot2v(sc0, qp.x, ka.x); dot2v(sc0, qp.y, ka.y);
            dot2v(sc1, qp.x, kb.x); dot2v(sc1, qp.y, kb.y);
            dot2v(sc2, qp.x, kc.x); dot2v(sc2, qp.y, kc.y);
        }
    }
    if (tid < 243) {
        float* sb = scores + (n * 2 + s) * 729 + ug * 27 + v0;
        atomicAdd(&sb[0], sc0);
        atomicAdd(&sb[1], sc1);
        atomicAdd(&sb[2], sc2);
    }
}

// ---------------------------------------------------------------------------
// k_att: attT[((n*2+s)*27+v)*16+e] = pack_bf16( att(u=2e,v), att(u=2e+1,v) )
// ---------------------------------------------------------------------------
__global__ void k_att(const float* __restrict__ scores,
                      const float* __restrict__ alphas,
                      const float* __restrict__ att0,
                      u32t* __restrict__ attT)
{
    int i = blockIdx.x * 256 + threadIdx.x;
    if (i >= NN * 2 * 27 * 16) return;
    int e = i & 15;
    int r = i >> 4;                 // (n*2+s)*27 + v
    int v = r % 27;
    int ns = r / 27;
    int s = ns & 1;
    const float* sb = scores + ns * 729;
    const float* ab = att0 + s * 729;
    float al = alphas[s];
    int u0 = 2 * e, u1 = 2 * e + 1;
    float a0 = (u0 < 27) ? tanhf(sb[u0 * 27 + v] * (1.f / 6400.f)) * al + ab[u0 * 27 + v] : 0.f;
    float a1 = (u1 < 27) ? tanhf(sb[u1 * 27 + v] * (1.f / 6400.f)) * al + ab[u1 * 27 + v] : 0.f;
    attT[i] = packbf(a0, a1);
}

// ---------------------------------------------------------------------------
// k_stage1: per (n, 9-t chunk). Lane = one pixel (tt,v).
// Two half-passes: each recomputes mm (rolled sc loop, mr[8] transient,
// fold-per-pair immediately) into acc[32] -> yp[h*16..]. Live regs ~60:
// no AGPR split, no shuttles. att_s stride 17 kills a4 bank conflicts.
// ---------------------------------------------------------------------------
__global__ __launch_bounds__(256, 4) void k_stage1(
    const float* __restrict__ x, const u32t* __restrict__ attT,
    const u32t* __restrict__ wfopk, const float* __restrict__ bfo,
    const u32t* __restrict__ wffpk, const float* __restrict__ bff,
    u16t* __restrict__ y2)
{
    const int tid = threadIdx.x;
    const int n = blockIdx.y, t0 = blockIdx.x * TB1;

    __shared__ __align__(16) u32t att_s[2 * 27 * 17];     // stride 17: bank-spread
    __shared__ __align__(16) u32t xs[64 * TB1 * 16];      // 36864 B
    const u16t* xs16 = (const u16t*)xs;

    for (int idx = tid; idx < 2 * 27 * 16; idx += 256) {
        int e = idx & 15, row = idx >> 4;
        att_s[row * 17 + e] = attT[n * 864 + idx];
    }
    for (int idx = tid; idx < 64 * TB1 * 32; idx += 256) {
        int u = idx & 31, ct = idx >> 5;
        int tt = ct % TB1, c = ct / TB1;
        int t = t0 + tt;
        float val = (u < 27 && t < TT) ? x[(n * 64 + c) * PIX + t * 27 + u] : 0.f;
        ((u16t*)xs)[idx] = f2bf(val);
    }
    __syncthreads();

    const int pcl = tid < PXS1 ? tid : PXS1 - 1;   // clamp: uniform control flow
    const int tt = pcl / 27, v = pcl - tt * 27;

    const u32t* aT0 = att_s + v * 17;
    u32t yp[32];

    #pragma unroll
    for (int h = 0; h < 2; ++h) {
        float acc[32];
        #pragma unroll
        for (int o = 0; o < 32; ++o) acc[o] = 0.f;

        for (int sc = 0; sc < 16; ++sc) {          // sc = s*8 + c8
            const int s = sc >> 3;
            const u32t* ab = aT0 + s * (27 * 17);
            const u32t* xb = xs + ((sc & 7) * 8 * TB1 + tt) * 16;
            float mr[8];
            #pragma unroll
            for (int k = 0; k < 8; ++k) mr[k] = 0.f;
            #pragma unroll
            for (int u4 = 0; u4 < 4; ++u4) {
                uint4 a4 = ld4u(ab + u4 * 4);
                #pragma unroll
                for (int k = 0; k < 8; ++k) {
                    uint4 x4 = ld4u(xb + k * (TB1 * 16) + u4 * 4);
                    dot2v(mr[k], a4.x, x4.x);
                    dot2v(mr[k], a4.y, x4.y);
                    dot2v(mr[k], a4.z, x4.z);
                    dot2v(mr[k], a4.w, x4.w);
                }
            }
            #pragma unroll
            for (int e = 0; e < 4; ++e) {
                u32t m = cvtpk(mr[2 * e], mr[2 * e + 1]);
                const u32t* wr = wfopk + (sc * 4 + e) * 64 + h * 32;  // uniform
                #pragma unroll
                for (int o = 0; o < 32; ++o) dot2s(acc[o], wr[o], m);
            }
        }

        // y1 half = lrelu(x + acc + bfo), packed
        #pragma unroll
        for (int e = 0; e < 16; ++e) {
            const int o0 = h * 32 + 2 * e;
            float xr0 = bf2f(xs16[(o0 * TB1 + tt) * 32 + v]);
            float xr1 = bf2f(xs16[((o0 + 1) * TB1 + tt) * 32 + v]);
            float y0 = lrelu(xr0 + acc[2 * e] + bfo[o0]);
            float y1v = lrelu(xr1 + acc[2 * e + 1] + bfo[o0 + 1]);
            yp[h * 16 + e] = cvtpk(y0, y1v);
        }
    }

    // ff stage: residual = x (still in xs)
    const bool wr_ok = (tid < PXS1) && (t0 + tt < TT);
    u16t* yb = y2 + (size_t)(n * 64) * PIX + (t0 + tt) * 27 + v;
    #pragma unroll
    for (int oc = 0; oc < 4; ++oc) {
        float a2[16];
        #pragma unroll
        for (int i = 0; i < 16; ++i) a2[i] = bff[oc * 16 + i];
        #pragma unroll
        for (int c2 = 0; c2 < 32; ++c2) {
            const u32t* wr = wffpk + c2 * 64 + oc * 16;   // uniform -> s_load
            #pragma unroll
            for (int i = 0; i < 16; ++i) dot2s(a2[i], wr[i], yp[c2]);
        }
        if (wr_ok) {
            #pragma unroll
            for (int i = 0; i < 16; ++i) {
                float res = bf2f(xs16[((oc * 16 + i) * TB1 + tt) * 32 + v]);
                yb[(size_t)(oc * 16 + i) * PIX] = f2bf(lrelu(res + a2[i]));
            }
        }
    }
}

// ---------------------------------------------------------------------------
// k_stage2: temporal 3x1 conv + BN + res + leaky. Lane = one pixel.
// Same half-pass structure: acc[32] per half, yrow re-read from LDS.
// ---------------------------------------------------------------------------
__global__ __launch_bounds__(256, 4) void k_stage2(
    const u16t* __restrict__ y2in, const u32t* __restrict__ wt2pk,
    const float* __restrict__ bft, float* __restrict__ out)
{
    const int tid = threadIdx.x;
    const int n = blockIdx.y, t0 = blockIdx.x * TB2;

    __shared__ __align__(16) u16t ys[(TB2 + 2) * 28 * 66];    // 40656 B

    for (int idx = tid; idx < 64 * (TB2 + 2) * 28; idx += 256) {
        int u = idx % 28, r = idx / 28;
        int tp = r % (TB2 + 2), c = r / (TB2 + 2);
        if (u >= 27) continue;
        int t = t0 - 1 + tp;
        ys[(tp * 28 + u) * 66 + c] = (t >= 0 && t < TT)
            ? y2in[(size_t)(n * 64 + c) * PIX + t * 27 + u] : (u16t)0;
    }
    __syncthreads();

    const int pcl = tid < PXS2 ? tid : PXS2 - 1;
    const int tt = pcl / 27, v = pcl - tt * 27;
    const bool wr_ok = (tid < PXS2) && (t0 + tt < TT);
    const u32t* ysu = (const u32t*)ys;
    float* ob = out + (size_t)(n * 64) * PIX + (t0 + tt) * 27 + v;

    #pragma unroll
    for (int h = 0; h < 2; ++h) {
        float acc[32];
        #pragma unroll
        for (int o = 0; o < 32; ++o) acc[o] = bft[h * 32 + o];

        #pragma unroll
        for (int kt = 0; kt < 3; ++kt) {
            const u32t* yrow = ysu + ((tt + kt) * 28 + v) * 33;
            #pragma unroll
            for (int c2 = 0; c2 < 32; ++c2) {
                u32t yp2 = yrow[c2];
                const u32t* wr = wt2pk + (kt * 32 + c2) * 64 + h * 32;  // uniform
                #pragma unroll
                for (int o = 0; o < 32; ++o) dot2s(acc[o], wr[o], yp2);
            }
        }

        if (wr_ok) {
            #pragma unroll
            for (int o = 0; o < 32; ++o) {
                const int oo = h * 32 + o;
                float res = bf2f(ys[((tt + 1) * 28 + v) * 66 + oo]);
                ob[(size_t)oo * PIX] = lrelu(res + acc[o]);
            }
        }
    }
}

// ---------------------------------------------------------------------------
extern "C" void kernel_launch(void* const* d_in, const int* in_sizes, int n_in,
                              void* d_out, int out_size, void* d_ws, size_t ws_size,
                              hipStream_t stream)
{
    const float* x      = (const float*)d_in[0];
    const float* w_in   = (const float*)d_in[1];
    const float* b_in   = (const float*)d_in[2];
    const float* alphas = (const float*)d_in[3];
    const float* att0   = (const float*)d_in[4];
    const float* w_outs = (const float*)d_in[5];
    const float* b_outs = (const float*)d_in[6];
    const float* bog    = (const float*)d_in[7];
    const float* bob    = (const float*)d_in[8];
    const float* bom    = (const float*)d_in[9];
    const float* bov    = (const float*)d_in[10];
    const float* w_ff   = (const float*)d_in[11];
    const float* b_ff   = (const float*)d_in[12];
    const float* bfg    = (const float*)d_in[13];
    const float* bfb    = (const float*)d_in[14];
    const float* bfm    = (const float*)d_in[15];
    const float* bfv    = (const float*)d_in[16];
    const float* w_t    = (const float*)d_in[17];
    const float* b_t    = (const float*)d_in[18];
    const float* btg    = (const float*)d_in[19];
    const float* btb    = (const float*)d_in[20];
    const float* btm    = (const float*)d_in[21];
    const float* btv    = (const float*)d_in[22];

    // ws layout (f32/u32 units):
    // pb 1792 | scores 46656 | attT 27648 | wfopk 4096 | bfo 64 |
    // wffpk 2048 | bff 64 | wt2pk 6144 | bft 64 | wqkpk 2048 | y2 (u16 XTOT)
    float* pbw    = (float*)d_ws;
    float* scores = pbw + 1792;
    u32t*  attT   = (u32t*)(scores + NSUV);
    u32t*  wfopk  = attT + 27648;
    float* bfo    = (float*)(wfopk + 4096);
    u32t*  wffpk  = (u32t*)(bfo + 64);
    float* bff    = (float*)(wffpk + 2048);
    u32t*  wt2pk  = (u32t*)(bff + 64);
    float* bft    = (float*)(wt2pk + 6144);
    u32t*  wqkpk  = (u32t*)(bft + 64);
    u16t*  y2     = (u16t*)(wqkpk + 2048);

    hipMemsetAsync(scores, 0, NSUV * sizeof(float), stream);

    k_prep<<<32, 256, 0, stream>>>(w_outs, b_outs, bog, bob, bom, bov,
                                   w_ff, b_ff, bfg, bfb, bfm, bfv,
                                   w_t, b_t, btg, btb, btm, btv, w_in,
                                   wfopk, bfo, wffpk, bff, wt2pk, bft, wqkpk);
    k_pbias<<<1, 256, 0, stream>>>(w_in, b_in, pbw);
    k_scores<<<dim3(NTS, 2, NN), 256, 0, stream>>>(x, wqkpk, pbw, scores);
    k_att<<<(NN * 2 * 27 * 16 + 255) / 256, 256, 0, stream>>>(scores, alphas, att0, attT);
    k_stage1<<<dim3(NT1, NN), 256, 0, stream>>>(x, attT, wfopk, bfo, wffpk, bff, y2);
    k_stage2<<<dim3(NT2, NN), 256, 0, stream>>>(y2, wt2pk, bft, (float*)d_out);
}

// Round 7
// 488.624 us; speedup vs baseline: 1.5672x; 1.5672x over previous
//
#include <hip/hip_runtime.h>
#include <hip/hip_bf16.h>
#include <math.h>

// STAttentionBlock  N=32 C=64 T=400 V=27 S=2 IC=16 — f32 I/O.
// Round 10: MFMA stage1 v2 (defensive resubmission of round 9):
//   (1) all packing of MFMA results uses pure-C packbf (no inline-asm cvtpk
//       fed by AGPR-resident MFMA outputs),
//   (2) mmL/y1L zero-initialized before first barrier (coverage holes ->
//       finite-wrong instead of NaN).
// Everything else identical to round 9. k_scores/k_stage2 = round 7 (known good).

typedef __hip_bfloat16 bf16;
typedef unsigned short u16t;
typedef unsigned int u32t;

using bf16x8 = __attribute__((ext_vector_type(8))) short;
using f32x4  = __attribute__((ext_vector_type(4))) float;

#define NN 32
#define CH 64
#define TT 400
#define VV 27
#define PIX 10800            // T*V
#define NSUV (32*2*27*27)    // 46656
#define XTOT (NN*CH*PIX)     // 22118400

#define TB1 4                // t per block, stage1 (112 pixels = 7 tiles of 16)
#define NT1 100
#define TB2 9
#define PXS2 (TB2*27)
#define NT2 45
#define TBS 9                // t per block, scores
#define NTS 45

__device__ __forceinline__ float lrelu(float x) { return x >= 0.f ? x : 0.1f * x; }
__device__ __forceinline__ float4 ld4(const float* p) { return *reinterpret_cast<const float4*>(p); }
__device__ __forceinline__ uint2 ld2u(const u32t* p) { return *reinterpret_cast<const uint2*>(p); }

// packed bf16 helpers
__device__ __forceinline__ u16t f2bf(float f) {
    return __bfloat16_as_ushort(__float2bfloat16(f));
}
__device__ __forceinline__ u32t packbf(float lo, float hi) {
    return ((u32t)f2bf(hi) << 16) | (u32t)f2bf(lo);
}
__device__ __forceinline__ float bf2f(u16t u) {
    return __uint_as_float(((u32t)u) << 16);
}
__device__ __forceinline__ u32t cvtpk(float lo, float hi) {
    u32t r;
    asm("v_cvt_pk_bf16_f32 %0, %1, %2" : "=v"(r) : "v"(lo), "v"(hi));
    return r;
}
// c += a.lo*b.lo + a.hi*b.hi  (bf16 pairs, f32 accum)
__device__ __forceinline__ void dot2v(float& c, u32t a, u32t b) {
    asm("v_dot2_f32_bf16 %0, %1, %2, %0" : "+v"(c) : "v"(a), "v"(b));
}
__device__ __forceinline__ void dot2s(float& c, u32t a_sgpr, u32t b) {
    asm("v_dot2_f32_bf16 %0, %1, %2, %0" : "+v"(c) : "s"(a_sgpr), "v"(b));
}

// ---------------------------------------------------------------------------
// k_prep: BN-folded weights.
//   wfoA[o*128+j] bf16 row-major (j = s*64+c)    conv_outs A-operand
//   wffA[o*64+c]  bf16 row-major                 ff A-operand
//   wt2pk[(kt*32+c2)*64+o] u32 pairs             tconv (stage2 dot2 path)
//   wqkpk[(sq*16+c)*32+cc2] u32 pairs            scores proj
//   bfo/bff/bft[o] = b*inv + beta
// ---------------------------------------------------------------------------
__global__ void k_prep(
    const float* __restrict__ w_outs, const float* __restrict__ b_outs,
    const float* __restrict__ go, const float* __restrict__ bo,
    const float* __restrict__ mo, const float* __restrict__ vo,
    const float* __restrict__ w_ff, const float* __restrict__ b_ff,
    const float* __restrict__ gf, const float* __restrict__ bf,
    const float* __restrict__ mf, const float* __restrict__ vf,
    const float* __restrict__ w_t, const float* __restrict__ b_t,
    const float* __restrict__ gt, const float* __restrict__ btb,
    const float* __restrict__ mt, const float* __restrict__ vt,
    const float* __restrict__ w_in,
    u16t* __restrict__ wfoA, float* __restrict__ bfo,
    u16t* __restrict__ wffA, float* __restrict__ bff,
    u32t* __restrict__ wt2pk, float* __restrict__ bft,
    u32t* __restrict__ wqkpk)
{
    const int total = 8192 + 4096 + 6144 + 192 + 2048;
    for (int idx = blockIdx.x * 256 + threadIdx.x; idx < total; idx += gridDim.x * 256) {
        if (idx < 8192) {
            int o = idx >> 7, j = idx & 127;
            float inv = go[o] * rsqrtf(vo[o] + 1e-5f);
            wfoA[idx] = f2bf(w_outs[o * 128 + j] * inv);
        } else if (idx < 12288) {
            int r = idx - 8192; int o = r >> 6, c = r & 63;
            float inv = gf[o] * rsqrtf(vf[o] + 1e-5f);
            wffA[r] = f2bf(w_ff[o * 64 + c] * inv);
        } else if (idx < 18432) {
            int r = idx - 12288; int o = r & 63, q = r >> 6;   // q < 96
            int kt = q >> 5, c2 = q & 31;
            float inv = gt[o] * rsqrtf(vt[o] + 1e-5f);
            wt2pk[r] = packbf(w_t[o * 192 + (2 * c2) * 3 + kt] * inv,
                              w_t[o * 192 + (2 * c2 + 1) * 3 + kt] * inv);
        } else if (idx < 18624) {
            int r = idx - 18432; int o = r & 63, which = r >> 6;
            if (which == 0) {
                float inv = go[o] * rsqrtf(vo[o] + 1e-5f);
                bfo[o] = b_outs[o] * inv + bo[o] - mo[o] * inv;
            } else if (which == 1) {
                float inv = gf[o] * rsqrtf(vf[o] + 1e-5f);
                bff[o] = b_ff[o] * inv + bf[o] - mf[o] * inv;
            } else {
                float inv = gt[o] * rsqrtf(vt[o] + 1e-5f);
                bft[o] = b_t[o] * inv + btb[o] - mt[o] * inv;
            }
        } else {
            int i = idx - 18624;                 // i < 2048
            int cc2 = i & 31, c = (i >> 5) & 15, sq = i >> 9;
            int s = sq >> 1, qk = sq & 1;
            int row = qk * 32 + s * 16 + c;
            wqkpk[i] = packbf(w_in[row * 64 + 2 * cc2], w_in[row * 64 + 2 * cc2 + 1]);
        }
    }
}

// ---------------------------------------------------------------------------
// k_pbias: pb[s*2+qk][c][u28] = b_in + sum_cc w_in * pe[cc][u]  (PE absorbed)
// ---------------------------------------------------------------------------
__global__ __launch_bounds__(256) void k_pbias(
    const float* __restrict__ w_in, const float* __restrict__ b_in,
    float* __restrict__ pb)
{
    __shared__ float pe[64 * 27];
    const int tid = threadIdx.x;
    for (int idx = tid; idx < 1728; idx += 256) {
        int c = idx / 27, u = idx % 27;
        float div = expf(-0.28782313662425575f * (float)(c >> 1));
        float ang = div * (float)u;
        pe[idx] = (c & 1) ? cosf(ang) : sinf(ang);
    }
    __syncthreads();
    for (int idx = tid; idx < 1792; idx += 256) {
        int u = idx % 28, r = idx / 28;
        int c = r % 16, sq = r / 16;
        if (u >= 27) { pb[idx] = 0.f; continue; }
        int s = sq >> 1, qk = sq & 1;
        int row = qk * 32 + s * 16 + c;
        float acc = b_in[row];
        for (int cc = 0; cc < 64; ++cc) acc += w_in[row * 64 + cc] * pe[cc * 27 + u];
        pb[idx] = acc;
    }
}

// ---------------------------------------------------------------------------
// k_scores: grid (45 tchunks, 2 s, 32 n). Lane = pixel (tt,u). (round 7)
// ---------------------------------------------------------------------------
__global__ __launch_bounds__(256, 4) void k_scores(
    const float* __restrict__ x, const u32t* __restrict__ wqkpk,
    const float* __restrict__ pb, float* __restrict__ scores)
{
    const int tid = threadIdx.x;
    const int s = blockIdx.y, n = blockIdx.z;
    const int t0 = blockIdx.x * TBS;

    __shared__ u32t qlds[TBS * 27 * 10];
    __shared__ u32t klds[TBS * 27 * 10];

    const int pcl = tid < 243 ? tid : 242;
    const int tt = pcl / 27, u = pcl - tt * 27;
    const int t = t0 + tt;
    const bool valid = (tid < 243) && (t < TT);

    u32t xp[32];
    const float* xb = x + (size_t)n * 64 * PIX + (size_t)(t < TT ? t : 0) * 27 + u;
    #pragma unroll
    for (int c2 = 0; c2 < 32; ++c2) {
        float v0 = xb[(size_t)(2 * c2) * PIX];
        float v1 = xb[(size_t)(2 * c2 + 1) * PIX];
        xp[c2] = cvtpk(v0, v1);
    }

    const float* pbq = pb + ((s * 2 + 0) * 16) * 28 + u;
    const float* pbk = pb + ((s * 2 + 1) * 16) * 28 + u;
    const u32t* wq = wqkpk + (s * 2 + 0) * 16 * 32;
    const u32t* wk = wqkpk + (s * 2 + 1) * 16 * 32;
    float qr[16], kr[16];
    #pragma unroll
    for (int c = 0; c < 16; ++c) { qr[c] = pbq[c * 28]; kr[c] = pbk[c * 28]; }
    #pragma unroll
    for (int c = 0; c < 16; ++c) {
        const u32t* wr = wq + c * 32;
        #pragma unroll
        for (int c2 = 0; c2 < 32; ++c2) dot2s(qr[c], wr[c2], xp[c2]);
    }
    #pragma unroll
    for (int c = 0; c < 16; ++c) {
        const u32t* wr = wk + c * 32;
        #pragma unroll
        for (int c2 = 0; c2 < 32; ++c2) dot2s(kr[c], wr[c2], xp[c2]);
    }

    if (tid < 243) {
        #pragma unroll
        for (int c2 = 0; c2 < 8; ++c2) {
            qlds[(tt * 27 + u) * 10 + c2] = valid ? cvtpk(qr[2 * c2], qr[2 * c2 + 1]) : 0u;
            klds[(tt * 27 + u) * 10 + c2] = valid ? cvtpk(kr[2 * c2], kr[2 * c2 + 1]) : 0u;
        }
    }
    __syncthreads();

    const int sid = tid < 243 ? tid : 242;
    const int ug = sid / 9, vg = sid % 9;
    const int v0 = vg * 3;
    float sc0 = 0.f, sc1 = 0.f, sc2 = 0.f;
    for (int t2 = 0; t2 < TBS; ++t2) {
        const u32t* qrow = qlds + (t2 * 27 + ug) * 10;
        const u32t* k0 = klds + (t2 * 27 + v0) * 10;
        #pragma unroll
        for (int c4 = 0; c4 < 4; ++c4) {
            uint2 qp = ld2u(qrow + c4 * 2);
            uint2 ka = ld2u(k0 + c4 * 2);
            uint2 kb = ld2u(k0 + 10 + c4 * 2);
            uint2 kc = ld2u(k0 + 20 + c4 * 2);
            dot2v(sc0, qp.x, ka.x); dot2v(sc0, qp.y, ka.y);
            dot2v(sc1, qp.x, kb.x); dot2v(sc1, qp.y, kb.y);
            dot2v(sc2, qp.x, kc.x); dot2v(sc2, qp.y, kc.y);
        }
    }
    if (tid < 243) {
        float* sb = scores + (n * 2 + s) * 729 + ug * 27 + v0;
        atomicAdd(&sb[0], sc0);
        atomicAdd(&sb[1], sc1);
        atomicAdd(&sb[2], sc2);
    }
}

// ---------------------------------------------------------------------------
// k_att: attTp[((n*2+s)*32+v)*16+e] = pack_bf16(att(2e,v), att(2e+1,v)),
// v-rows 27..31 zero (MFMA B-operand padding).
// ---------------------------------------------------------------------------
__global__ void k_att(const float* __restrict__ scores,
                      const float* __restrict__ alphas,
                      const float* __restrict__ att0,
                      u32t* __restrict__ attTp)
{
    int i = blockIdx.x * 256 + threadIdx.x;
    if (i >= NN * 2 * 32 * 16) return;
    int e = i & 15;
    int r = i >> 4;                 // (n*2+s)*32 + v
    int v = r & 31;
    int ns = r >> 5;
    int s = ns & 1;
    if (v >= 27) { attTp[i] = 0u; return; }
    const float* sb = scores + ns * 729;
    const float* ab = att0 + s * 729;
    float al = alphas[s];
    int u0 = 2 * e, u1 = 2 * e + 1;
    float a0 = (u0 < 27) ? tanhf(sb[u0 * 27 + v] * (1.f / 6400.f)) * al + ab[u0 * 27 + v] : 0.f;
    float a1 = (u1 < 27) ? tanhf(sb[u1 * 27 + v] * (1.f / 6400.f)) * al + ab[u1 * 27 + v] : 0.f;
    attTp[i] = packbf(a0, a1);
}

// ---------------------------------------------------------------------------
// k_stage1 (MFMA v2): per (n, 4-t chunk). p = tt*28+v (112 px = 7 tiles).
//   phase mm  : wave w = t; D[c][v] = mfma(x[c][u], att[u][v]) -> mmL[p][j]
//   phase fold: wave w = o-tile; y1 = lrelu(x + mfma(Wfo, mm) + bfo) -> y1L
//   phase ff  : y2 = lrelu(x + mfma(Wff, y1) + bff) -> global (bf16)
// Fragment maps (CDNA): A[m][k]: m=lane%16, k=(lane/16)*8+e; B[k][n]:
// n=lane%16, k=(lane/16)*8+e; D[m][n]: n=lane%16, m=(lane/16)*4+reg.
// v2: packbf (pure C) for all D packing; mmL/y1L zero-initialized.
// ---------------------------------------------------------------------------
__global__ __launch_bounds__(256, 2) void k_stage1(
    const float* __restrict__ x, const u32t* __restrict__ attTp,
    const u16t* __restrict__ wfoA, const float* __restrict__ bfo,
    const u16t* __restrict__ wffA, const float* __restrict__ bff,
    u16t* __restrict__ y2)
{
    const int tid = threadIdx.x;
    const int n = blockIdx.y, t0 = blockIdx.x * TB1;
    const int w = tid >> 6, li = tid & 15, g = (tid >> 4) & 3;

    __shared__ __align__(16) u16t xs[64 * TB1 * 32];      // 16384 B [c*4+tt][32u]
    __shared__ __align__(16) u32t mmL[112 * 68];          // 30464 B [p][j-pair]
    __shared__ __align__(16) u32t y1L[112 * 34];          // 15232 B [p][c-pair]

    for (int i = tid; i < 8192; i += 256) {
        int u = i & 31, ct = i >> 5;
        int tt = ct & 3, c = ct >> 2;
        float val = (u < 27) ? x[(size_t)(n * 64 + c) * PIX + (t0 + tt) * 27 + u] : 0.f;
        xs[i] = f2bf(val);
    }
    for (int i = tid; i < 112 * 68; i += 256) mmL[i] = 0u;
    for (int i = tid; i < 112 * 34; i += 256) y1L[i] = 0u;
    __syncthreads();

    // ---- mm: wave w handles t = t0 + w ----
    {
        bf16x8 ax[4];
        #pragma unroll
        for (int Mt = 0; Mt < 4; ++Mt)
            ax[Mt] = *reinterpret_cast<const bf16x8*>(&xs[((Mt * 16 + li) * 4 + w) * 32 + g * 8]);
        const u16t* attp16 = reinterpret_cast<const u16t*>(attTp);
        #pragma unroll
        for (int s = 0; s < 2; ++s) {
            #pragma unroll
            for (int Nt = 0; Nt < 2; ++Nt) {
                bf16x8 b = *reinterpret_cast<const bf16x8*>(
                    &attp16[(((n * 2 + s) * 32) + Nt * 16 + li) * 32 + g * 8]);
                const int v = Nt * 16 + li;
                #pragma unroll
                for (int Mt = 0; Mt < 4; ++Mt) {
                    f32x4 d = {0.f, 0.f, 0.f, 0.f};
                    d = __builtin_amdgcn_mfma_f32_16x16x32_bf16(ax[Mt], b, d, 0, 0, 0);
                    if (v < 28) {
                        const int p = w * 28 + v;
                        const int j2 = s * 32 + Mt * 8 + g * 2;
                        mmL[p * 68 + j2]     = packbf(d[0], d[1]);
                        mmL[p * 68 + j2 + 1] = packbf(d[2], d[3]);
                    }
                }
            }
        }
    }
    __syncthreads();

    // ---- fold: wave w owns o-rows [w*16, w*16+16) ----
    const int o0 = w * 16 + g * 4;
    {
        bf16x8 aw[4];
        #pragma unroll
        for (int Ks = 0; Ks < 4; ++Ks)
            aw[Ks] = *reinterpret_cast<const bf16x8*>(&wfoA[(w * 16 + li) * 128 + Ks * 32 + g * 8]);
        float4 bf4 = ld4(&bfo[o0]);
        #pragma unroll
        for (int Nt = 0; Nt < 7; ++Nt) {
            f32x4 d = {0.f, 0.f, 0.f, 0.f};
            #pragma unroll
            for (int Ks = 0; Ks < 4; ++Ks) {
                bf16x8 b = *reinterpret_cast<const bf16x8*>(&mmL[(Nt * 16 + li) * 68 + Ks * 16 + g * 4]);
                d = __builtin_amdgcn_mfma_f32_16x16x32_bf16(aw[Ks], b, d, 0, 0, 0);
            }
            const int p = Nt * 16 + li;
            const int tt = p / 28, v = p - tt * 28;
            float ya = lrelu(bf2f(xs[((o0 + 0) * 4 + tt) * 32 + v]) + d[0] + bf4.x);
            float yb = lrelu(bf2f(xs[((o0 + 1) * 4 + tt) * 32 + v]) + d[1] + bf4.y);
            float yc = lrelu(bf2f(xs[((o0 + 2) * 4 + tt) * 32 + v]) + d[2] + bf4.z);
            float yd = lrelu(bf2f(xs[((o0 + 3) * 4 + tt) * 32 + v]) + d[3] + bf4.w);
            y1L[p * 34 + w * 8 + g * 2]     = packbf(ya, yb);
            y1L[p * 34 + w * 8 + g * 2 + 1] = packbf(yc, yd);
        }
    }
    __syncthreads();

    // ---- ff: wave w owns o-rows [w*16, w*16+16) ----
    {
        bf16x8 af[2];
        #pragma unroll
        for (int Ks = 0; Ks < 2; ++Ks)
            af[Ks] = *reinterpret_cast<const bf16x8*>(&wffA[(w * 16 + li) * 64 + Ks * 32 + g * 8]);
        float4 bff4 = ld4(&bff[o0]);
        #pragma unroll
        for (int Nt = 0; Nt < 7; ++Nt) {
            f32x4 d = {0.f, 0.f, 0.f, 0.f};
            #pragma unroll
            for (int Ks = 0; Ks < 2; ++Ks) {
                union { uint2 u2[2]; bf16x8 v8; } bu;
                bu.u2[0] = *reinterpret_cast<const uint2*>(&y1L[(Nt * 16 + li) * 34 + Ks * 16 + g * 4]);
                bu.u2[1] = *reinterpret_cast<const uint2*>(&y1L[(Nt * 16 + li) * 34 + Ks * 16 + g * 4 + 2]);
                d = __builtin_amdgcn_mfma_f32_16x16x32_bf16(af[Ks], bu.v8, d, 0, 0, 0);
            }
            const int p = Nt * 16 + li;
            const int tt = p / 28, v = p - tt * 28;
            if (v < 27) {
                u16t* yb0 = y2 + (size_t)(n * 64) * PIX + (size_t)(t0 + tt) * 27 + v;
                yb0[(size_t)(o0 + 0) * PIX] = f2bf(lrelu(bf2f(xs[((o0 + 0) * 4 + tt) * 32 + v]) + d[0] + bff4.x));
                yb0[(size_t)(o0 + 1) * PIX] = f2bf(lrelu(bf2f(xs[((o0 + 1) * 4 + tt) * 32 + v]) + d[1] + bff4.y));
                yb0[(size_t)(o0 + 2) * PIX] = f2bf(lrelu(bf2f(xs[((o0 + 2) * 4 + tt) * 32 + v]) + d[2] + bff4.z));
                yb0[(size_t)(o0 + 3) * PIX] = f2bf(lrelu(bf2f(xs[((o0 + 3) * 4 + tt) * 32 + v]) + d[3] + bff4.w));
            }
        }
    }
}

// ---------------------------------------------------------------------------
// k_stage2: temporal 3x1 conv + BN + res + leaky (round-7 dot2s version).
// ---------------------------------------------------------------------------
__global__ __launch_bounds__(256, 3) void k_stage2(
    const u16t* __restrict__ y2in, const u32t* __restrict__ wt2pk,
    const float* __restrict__ bft, float* __restrict__ out)
{
    const int tid = threadIdx.x;
    const int n = blockIdx.y, t0 = blockIdx.x * TB2;

    __shared__ __align__(16) u16t ys[(TB2 + 2) * 28 * 66];    // 40656 B

    for (int idx = tid; idx < 64 * (TB2 + 2) * 28; idx += 256) {
        int u = idx % 28, r = idx / 28;
        int tp = r % (TB2 + 2), c = r / (TB2 + 2);
        if (u >= 27) continue;
        int t = t0 - 1 + tp;
        ys[(tp * 28 + u) * 66 + c] = (t >= 0 && t < TT)
            ? y2in[(size_t)(n * 64 + c) * PIX + t * 27 + u] : (u16t)0;
    }
    __syncthreads();

    const int pcl = tid < PXS2 ? tid : PXS2 - 1;
    const int tt = pcl / 27, v = pcl - tt * 27;

    float acc[64];
    #pragma unroll
    for (int o = 0; o < 64; ++o) acc[o] = bft[o];

    const u32t* ysu = (const u32t*)ys;
    #pragma unroll
    for (int kt = 0; kt < 3; ++kt) {
        const u32t* yrow = ysu + ((tt + kt) * 28 + v) * 33;
        #pragma unroll 8
        for (int c2 = 0; c2 < 32; ++c2) {
            u32t yp2 = yrow[c2];
            const u32t* wr = wt2pk + (kt * 32 + c2) * 64;    // uniform -> s_load
            #pragma unroll
            for (int o = 0; o < 64; ++o) dot2s(acc[o], wr[o], yp2);
        }
    }

    if (tid < PXS2 && t0 + tt < TT) {
        float* ob = out + (size_t)(n * 64) * PIX + (t0 + tt) * 27 + v;
        #pragma unroll
        for (int o = 0; o < 64; ++o) {
            float res = bf2f(ys[((tt + 1) * 28 + v) * 66 + o]);
            ob[(size_t)o * PIX] = lrelu(res + acc[o]);
        }
    }
}

// ---------------------------------------------------------------------------
extern "C" void kernel_launch(void* const* d_in, const int* in_sizes, int n_in,
                              void* d_out, int out_size, void* d_ws, size_t ws_size,
                              hipStream_t stream)
{
    const float* x      = (const float*)d_in[0];
    const float* w_in   = (const float*)d_in[1];
    const float* b_in   = (const float*)d_in[2];
    const float* alphas = (const float*)d_in[3];
    const float* att0   = (const float*)d_in[4];
    const float* w_outs = (const float*)d_in[5];
    const float* b_outs = (const float*)d_in[6];
    const float* bog    = (const float*)d_in[7];
    const float* bob    = (const float*)d_in[8];
    const float* bom    = (const float*)d_in[9];
    const float* bov    = (const float*)d_in[10];
    const float* w_ff   = (const float*)d_in[11];
    const float* b_ff   = (const float*)d_in[12];
    const float* bfg    = (const float*)d_in[13];
    const float* bfb    = (const float*)d_in[14];
    const float* bfm    = (const float*)d_in[15];
    const float* bfv    = (const float*)d_in[16];
    const float* w_t    = (const float*)d_in[17];
    const float* b_t    = (const float*)d_in[18];
    const float* btg    = (const float*)d_in[19];
    const float* btb    = (const float*)d_in[20];
    const float* btm    = (const float*)d_in[21];
    const float* btv    = (const float*)d_in[22];

    // ws layout (u32 units):
    // pb 1792 | scores 46656 | attTp 32768 | wfoA 4096 | wffA 2048 |
    // wt2pk 6144 | bfo 64 | bff 64 | bft 64 | wqkpk 2048 | y2 (u16 XTOT)
    float* pbw    = (float*)d_ws;
    float* scores = pbw + 1792;
    u32t*  attTp  = (u32t*)(scores + NSUV);
    u16t*  wfoA   = (u16t*)(attTp + 32768);
    u16t*  wffA   = (u16t*)((u32t*)wfoA + 4096);
    u32t*  wt2pk  = (u32t*)wffA + 2048;
    float* bfo    = (float*)(wt2pk + 6144);
    float* bff    = bfo + 64;
    float* bft    = bff + 64;
    u32t*  wqkpk  = (u32t*)(bft + 64);
    u16t*  y2     = (u16t*)(wqkpk + 2048);

    hipMemsetAsync(scores, 0, NSUV * sizeof(float), stream);

    k_prep<<<32, 256, 0, stream>>>(w_outs, b_outs, bog, bob, bom, bov,
                                   w_ff, b_ff, bfg, bfb, bfm, bfv,
                                   w_t, b_t, btg, btb, btm, btv, w_in,
                                   wfoA, bfo, wffA, bff, wt2pk, bft, wqkpk);
    k_pbias<<<1, 256, 0, stream>>>(w_in, b_in, pbw);
    k_scores<<<dim3(NTS, 2, NN), 256, 0, stream>>>(x, wqkpk, pbw, scores);
    k_att<<<(NN * 2 * 32 * 16 + 255) / 256, 256, 0, stream>>>(scores, alphas, att0, attTp);
    k_stage1<<<dim3(NT1, NN), 256, 0, stream>>>(x, attTp, wfoA, bfo, wffA, bff, y2);
    k_stage2<<<dim3(NT2, NN), 256, 0, stream>>>(y2, wt2pk, bft, (float*)d_out);
}

// Round 8
// 421.019 us; speedup vs baseline: 1.8189x; 1.1606x over previous
//
#include <hip/hip_runtime.h>
#include <hip/hip_bf16.h>
#include <math.h>

// STAttentionBlock  N=32 C=64 T=400 V=27 S=2 IC=16 — f32 I/O.
// Round 11: k_stage2 ported to MFMA using the (now verified) stage1 fold
// template. K ordered k' = kt*64+c so B-fragments are contiguous bf16x8 in
// the transposed [t'][v][c] LDS tile (stride 72). 42 MFMA/wave, fused
// BN+res+lrelu epilogue. stage1 = round-10 MFMA (verified). k_scores = round 7.

typedef __hip_bfloat16 bf16;
typedef unsigned short u16t;
typedef unsigned int u32t;

using bf16x8 = __attribute__((ext_vector_type(8))) short;
using f32x4  = __attribute__((ext_vector_type(4))) float;

#define NN 32
#define CH 64
#define TT 400
#define VV 27
#define PIX 10800            // T*V
#define NSUV (32*2*27*27)    // 46656
#define XTOT (NN*CH*PIX)     // 22118400

#define TB1 4                // t per block, stage1 (112 pixels = 7 tiles of 16)
#define NT1 100
#define TB2 4                // t per block, stage2 (MFMA)
#define NT2 100
#define TBS 9                // t per block, scores
#define NTS 45

__device__ __forceinline__ float lrelu(float x) { return x >= 0.f ? x : 0.1f * x; }
__device__ __forceinline__ float4 ld4(const float* p) { return *reinterpret_cast<const float4*>(p); }
__device__ __forceinline__ uint2 ld2u(const u32t* p) { return *reinterpret_cast<const uint2*>(p); }

// packed bf16 helpers
__device__ __forceinline__ u16t f2bf(float f) {
    return __bfloat16_as_ushort(__float2bfloat16(f));
}
__device__ __forceinline__ u32t packbf(float lo, float hi) {
    return ((u32t)f2bf(hi) << 16) | (u32t)f2bf(lo);
}
__device__ __forceinline__ float bf2f(u16t u) {
    return __uint_as_float(((u32t)u) << 16);
}
__device__ __forceinline__ u32t cvtpk(float lo, float hi) {
    u32t r;
    asm("v_cvt_pk_bf16_f32 %0, %1, %2" : "=v"(r) : "v"(lo), "v"(hi));
    return r;
}
// c += a.lo*b.lo + a.hi*b.hi  (bf16 pairs, f32 accum)
__device__ __forceinline__ void dot2v(float& c, u32t a, u32t b) {
    asm("v_dot2_f32_bf16 %0, %1, %2, %0" : "+v"(c) : "v"(a), "v"(b));
}
__device__ __forceinline__ void dot2s(float& c, u32t a_sgpr, u32t b) {
    asm("v_dot2_f32_bf16 %0, %1, %2, %0" : "+v"(c) : "s"(a_sgpr), "v"(b));
}

// ---------------------------------------------------------------------------
// k_prep: BN-folded weights.
//   wfoA[o*128+j]        bf16 row-major (j = s*64+c)   conv_outs A-operand
//   wffA[o*64+c]         bf16 row-major                ff A-operand
//   wtA [o*192+kt*64+c]  bf16 row-major (k' kt-major)  tconv A-operand
//   wqkpk[(sq*16+c)*32+cc2] u32 pairs                  scores proj
//   bfo/bff/bft[o] = b*inv + beta
// ---------------------------------------------------------------------------
__global__ void k_prep(
    const float* __restrict__ w_outs, const float* __restrict__ b_outs,
    const float* __restrict__ go, const float* __restrict__ bo,
    const float* __restrict__ mo, const float* __restrict__ vo,
    const float* __restrict__ w_ff, const float* __restrict__ b_ff,
    const float* __restrict__ gf, const float* __restrict__ bf,
    const float* __restrict__ mf, const float* __restrict__ vf,
    const float* __restrict__ w_t, const float* __restrict__ b_t,
    const float* __restrict__ gt, const float* __restrict__ btb,
    const float* __restrict__ mt, const float* __restrict__ vt,
    const float* __restrict__ w_in,
    u16t* __restrict__ wfoA, float* __restrict__ bfo,
    u16t* __restrict__ wffA, float* __restrict__ bff,
    u16t* __restrict__ wtA, float* __restrict__ bft,
    u32t* __restrict__ wqkpk)
{
    const int total = 8192 + 4096 + 12288 + 192 + 2048;
    for (int idx = blockIdx.x * 256 + threadIdx.x; idx < total; idx += gridDim.x * 256) {
        if (idx < 8192) {
            int o = idx >> 7, j = idx & 127;
            float inv = go[o] * rsqrtf(vo[o] + 1e-5f);
            wfoA[idx] = f2bf(w_outs[o * 128 + j] * inv);
        } else if (idx < 12288) {
            int r = idx - 8192; int o = r >> 6, c = r & 63;
            float inv = gf[o] * rsqrtf(vf[o] + 1e-5f);
            wffA[r] = f2bf(w_ff[o * 64 + c] * inv);
        } else if (idx < 24576) {
            int r = idx - 12288;                  // r = o*192 + kt*64 + c
            int o = r / 192, k2 = r % 192;
            int kt = k2 >> 6, c = k2 & 63;
            float inv = gt[o] * rsqrtf(vt[o] + 1e-5f);
            wtA[r] = f2bf(w_t[o * 192 + c * 3 + kt] * inv);
        } else if (idx < 24768) {
            int r = idx - 24576; int o = r & 63, which = r >> 6;
            if (which == 0) {
                float inv = go[o] * rsqrtf(vo[o] + 1e-5f);
                bfo[o] = b_outs[o] * inv + bo[o] - mo[o] * inv;
            } else if (which == 1) {
                float inv = gf[o] * rsqrtf(vf[o] + 1e-5f);
                bff[o] = b_ff[o] * inv + bf[o] - mf[o] * inv;
            } else {
                float inv = gt[o] * rsqrtf(vt[o] + 1e-5f);
                bft[o] = b_t[o] * inv + btb[o] - mt[o] * inv;
            }
        } else {
            int i = idx - 24768;                 // i < 2048
            int cc2 = i & 31, c = (i >> 5) & 15, sq = i >> 9;
            int s = sq >> 1, qk = sq & 1;
            int row = qk * 32 + s * 16 + c;
            wqkpk[i] = packbf(w_in[row * 64 + 2 * cc2], w_in[row * 64 + 2 * cc2 + 1]);
        }
    }
}

// ---------------------------------------------------------------------------
// k_pbias: pb[s*2+qk][c][u28] = b_in + sum_cc w_in * pe[cc][u]  (PE absorbed)
// ---------------------------------------------------------------------------
__global__ __launch_bounds__(256) void k_pbias(
    const float* __restrict__ w_in, const float* __restrict__ b_in,
    float* __restrict__ pb)
{
    __shared__ float pe[64 * 27];
    const int tid = threadIdx.x;
    for (int idx = tid; idx < 1728; idx += 256) {
        int c = idx / 27, u = idx % 27;
        float div = expf(-0.28782313662425575f * (float)(c >> 1));
        float ang = div * (float)u;
        pe[idx] = (c & 1) ? cosf(ang) : sinf(ang);
    }
    __syncthreads();
    for (int idx = tid; idx < 1792; idx += 256) {
        int u = idx % 28, r = idx / 28;
        int c = r % 16, sq = r / 16;
        if (u >= 27) { pb[idx] = 0.f; continue; }
        int s = sq >> 1, qk = sq & 1;
        int row = qk * 32 + s * 16 + c;
        float acc = b_in[row];
        for (int cc = 0; cc < 64; ++cc) acc += w_in[row * 64 + cc] * pe[cc * 27 + u];
        pb[idx] = acc;
    }
}

// ---------------------------------------------------------------------------
// k_scores: grid (45 tchunks, 2 s, 32 n). Lane = pixel (tt,u). (round 7)
// ---------------------------------------------------------------------------
__global__ __launch_bounds__(256, 4) void k_scores(
    const float* __restrict__ x, const u32t* __restrict__ wqkpk,
    const float* __restrict__ pb, float* __restrict__ scores)
{
    const int tid = threadIdx.x;
    const int s = blockIdx.y, n = blockIdx.z;
    const int t0 = blockIdx.x * TBS;

    __shared__ u32t qlds[TBS * 27 * 10];
    __shared__ u32t klds[TBS * 27 * 10];

    const int pcl = tid < 243 ? tid : 242;
    const int tt = pcl / 27, u = pcl - tt * 27;
    const int t = t0 + tt;
    const bool valid = (tid < 243) && (t < TT);

    u32t xp[32];
    const float* xb = x + (size_t)n * 64 * PIX + (size_t)(t < TT ? t : 0) * 27 + u;
    #pragma unroll
    for (int c2 = 0; c2 < 32; ++c2) {
        float v0 = xb[(size_t)(2 * c2) * PIX];
        float v1 = xb[(size_t)(2 * c2 + 1) * PIX];
        xp[c2] = cvtpk(v0, v1);
    }

    const float* pbq = pb + ((s * 2 + 0) * 16) * 28 + u;
    const float* pbk = pb + ((s * 2 + 1) * 16) * 28 + u;
    const u32t* wq = wqkpk + (s * 2 + 0) * 16 * 32;
    const u32t* wk = wqkpk + (s * 2 + 1) * 16 * 32;
    float qr[16], kr[16];
    #pragma unroll
    for (int c = 0; c < 16; ++c) { qr[c] = pbq[c * 28]; kr[c] = pbk[c * 28]; }
    #pragma unroll
    for (int c = 0; c < 16; ++c) {
        const u32t* wr = wq + c * 32;
        #pragma unroll
        for (int c2 = 0; c2 < 32; ++c2) dot2s(qr[c], wr[c2], xp[c2]);
    }
    #pragma unroll
    for (int c = 0; c < 16; ++c) {
        const u32t* wr = wk + c * 32;
        #pragma unroll
        for (int c2 = 0; c2 < 32; ++c2) dot2s(kr[c], wr[c2], xp[c2]);
    }

    if (tid < 243) {
        #pragma unroll
        for (int c2 = 0; c2 < 8; ++c2) {
            qlds[(tt * 27 + u) * 10 + c2] = valid ? cvtpk(qr[2 * c2], qr[2 * c2 + 1]) : 0u;
            klds[(tt * 27 + u) * 10 + c2] = valid ? cvtpk(kr[2 * c2], kr[2 * c2 + 1]) : 0u;
        }
    }
    __syncthreads();

    const int sid = tid < 243 ? tid : 242;
    const int ug = sid / 9, vg = sid % 9;
    const int v0 = vg * 3;
    float sc0 = 0.f, sc1 = 0.f, sc2 = 0.f;
    for (int t2 = 0; t2 < TBS; ++t2) {
        const u32t* qrow = qlds + (t2 * 27 + ug) * 10;
        const u32t* k0 = klds + (t2 * 27 + v0) * 10;
        #pragma unroll
        for (int c4 = 0; c4 < 4; ++c4) {
            uint2 qp = ld2u(qrow + c4 * 2);
            uint2 ka = ld2u(k0 + c4 * 2);
            uint2 kb = ld2u(k0 + 10 + c4 * 2);
            uint2 kc = ld2u(k0 + 20 + c4 * 2);
            dot2v(sc0, qp.x, ka.x); dot2v(sc0, qp.y, ka.y);
            dot2v(sc1, qp.x, kb.x); dot2v(sc1, qp.y, kb.y);
            dot2v(sc2, qp.x, kc.x); dot2v(sc2, qp.y, kc.y);
        }
    }
    if (tid < 243) {
        float* sb = scores + (n * 2 + s) * 729 + ug * 27 + v0;
        atomicAdd(&sb[0], sc0);
        atomicAdd(&sb[1], sc1);
        atomicAdd(&sb[2], sc2);
    }
}

// ---------------------------------------------------------------------------
// k_att: attTp[((n*2+s)*32+v)*16+e] = pack_bf16(att(2e,v), att(2e+1,v)),
// v-rows 27..31 zero (MFMA B-operand padding).
// ---------------------------------------------------------------------------
__global__ void k_att(const float* __restrict__ scores,
                      const float* __restrict__ alphas,
                      const float* __restrict__ att0,
                      u32t* __restrict__ attTp)
{
    int i = blockIdx.x * 256 + threadIdx.x;
    if (i >= NN * 2 * 32 * 16) return;
    int e = i & 15;
    int r = i >> 4;                 // (n*2+s)*32 + v
    int v = r & 31;
    int ns = r >> 5;
    int s = ns & 1;
    if (v >= 27) { attTp[i] = 0u; return; }
    const float* sb = scores + ns * 729;
    const float* ab = att0 + s * 729;
    float al = alphas[s];
    int u0 = 2 * e, u1 = 2 * e + 1;
    float a0 = (u0 < 27) ? tanhf(sb[u0 * 27 + v] * (1.f / 6400.f)) * al + ab[u0 * 27 + v] : 0.f;
    float a1 = (u1 < 27) ? tanhf(sb[u1 * 27 + v] * (1.f / 6400.f)) * al + ab[u1 * 27 + v] : 0.f;
    attTp[i] = packbf(a0, a1);
}

// ---------------------------------------------------------------------------
// k_stage1 (MFMA, verified round 10): per (n, 4-t chunk). p = tt*28+v.
// ---------------------------------------------------------------------------
__global__ __launch_bounds__(256, 2) void k_stage1(
    const float* __restrict__ x, const u32t* __restrict__ attTp,
    const u16t* __restrict__ wfoA, const float* __restrict__ bfo,
    const u16t* __restrict__ wffA, const float* __restrict__ bff,
    u16t* __restrict__ y2)
{
    const int tid = threadIdx.x;
    const int n = blockIdx.y, t0 = blockIdx.x * TB1;
    const int w = tid >> 6, li = tid & 15, g = (tid >> 4) & 3;

    __shared__ __align__(16) u16t xs[64 * TB1 * 32];      // 16384 B [c*4+tt][32u]
    __shared__ __align__(16) u32t mmL[112 * 68];          // 30464 B [p][j-pair]
    __shared__ __align__(16) u32t y1L[112 * 34];          // 15232 B [p][c-pair]

    for (int i = tid; i < 8192; i += 256) {
        int u = i & 31, ct = i >> 5;
        int tt = ct & 3, c = ct >> 2;
        float val = (u < 27) ? x[(size_t)(n * 64 + c) * PIX + (t0 + tt) * 27 + u] : 0.f;
        xs[i] = f2bf(val);
    }
    for (int i = tid; i < 112 * 68; i += 256) mmL[i] = 0u;
    for (int i = tid; i < 112 * 34; i += 256) y1L[i] = 0u;
    __syncthreads();

    // ---- mm: wave w handles t = t0 + w ----
    {
        bf16x8 ax[4];
        #pragma unroll
        for (int Mt = 0; Mt < 4; ++Mt)
            ax[Mt] = *reinterpret_cast<const bf16x8*>(&xs[((Mt * 16 + li) * 4 + w) * 32 + g * 8]);
        const u16t* attp16 = reinterpret_cast<const u16t*>(attTp);
        #pragma unroll
        for (int s = 0; s < 2; ++s) {
            #pragma unroll
            for (int Nt = 0; Nt < 2; ++Nt) {
                bf16x8 b = *reinterpret_cast<const bf16x8*>(
                    &attp16[(((n * 2 + s) * 32) + Nt * 16 + li) * 32 + g * 8]);
                const int v = Nt * 16 + li;
                #pragma unroll
                for (int Mt = 0; Mt < 4; ++Mt) {
                    f32x4 d = {0.f, 0.f, 0.f, 0.f};
                    d = __builtin_amdgcn_mfma_f32_16x16x32_bf16(ax[Mt], b, d, 0, 0, 0);
                    if (v < 28) {
                        const int p = w * 28 + v;
                        const int j2 = s * 32 + Mt * 8 + g * 2;
                        mmL[p * 68 + j2]     = packbf(d[0], d[1]);
                        mmL[p * 68 + j2 + 1] = packbf(d[2], d[3]);
                    }
                }
            }
        }
    }
    __syncthreads();

    // ---- fold: wave w owns o-rows [w*16, w*16+16) ----
    const int o0 = w * 16 + g * 4;
    {
        bf16x8 aw[4];
        #pragma unroll
        for (int Ks = 0; Ks < 4; ++Ks)
            aw[Ks] = *reinterpret_cast<const bf16x8*>(&wfoA[(w * 16 + li) * 128 + Ks * 32 + g * 8]);
        float4 bf4 = ld4(&bfo[o0]);
        #pragma unroll
        for (int Nt = 0; Nt < 7; ++Nt) {
            f32x4 d = {0.f, 0.f, 0.f, 0.f};
            #pragma unroll
            for (int Ks = 0; Ks < 4; ++Ks) {
                bf16x8 b = *reinterpret_cast<const bf16x8*>(&mmL[(Nt * 16 + li) * 68 + Ks * 16 + g * 4]);
                d = __builtin_amdgcn_mfma_f32_16x16x32_bf16(aw[Ks], b, d, 0, 0, 0);
            }
            const int p = Nt * 16 + li;
            const int tt = p / 28, v = p - tt * 28;
            float ya = lrelu(bf2f(xs[((o0 + 0) * 4 + tt) * 32 + v]) + d[0] + bf4.x);
            float yb = lrelu(bf2f(xs[((o0 + 1) * 4 + tt) * 32 + v]) + d[1] + bf4.y);
            float yc = lrelu(bf2f(xs[((o0 + 2) * 4 + tt) * 32 + v]) + d[2] + bf4.z);
            float yd = lrelu(bf2f(xs[((o0 + 3) * 4 + tt) * 32 + v]) + d[3] + bf4.w);
            y1L[p * 34 + w * 8 + g * 2]     = packbf(ya, yb);
            y1L[p * 34 + w * 8 + g * 2 + 1] = packbf(yc, yd);
        }
    }
    __syncthreads();

    // ---- ff: wave w owns o-rows [w*16, w*16+16) ----
    {
        bf16x8 af[2];
        #pragma unroll
        for (int Ks = 0; Ks < 2; ++Ks)
            af[Ks] = *reinterpret_cast<const bf16x8*>(&wffA[(w * 16 + li) * 64 + Ks * 32 + g * 8]);
        float4 bff4 = ld4(&bff[o0]);
        #pragma unroll
        for (int Nt = 0; Nt < 7; ++Nt) {
            f32x4 d = {0.f, 0.f, 0.f, 0.f};
            #pragma unroll
            for (int Ks = 0; Ks < 2; ++Ks) {
                union { uint2 u2[2]; bf16x8 v8; } bu;
                bu.u2[0] = *reinterpret_cast<const uint2*>(&y1L[(Nt * 16 + li) * 34 + Ks * 16 + g * 4]);
                bu.u2[1] = *reinterpret_cast<const uint2*>(&y1L[(Nt * 16 + li) * 34 + Ks * 16 + g * 4 + 2]);
                d = __builtin_amdgcn_mfma_f32_16x16x32_bf16(af[Ks], bu.v8, d, 0, 0, 0);
            }
            const int p = Nt * 16 + li;
            const int tt = p / 28, v = p - tt * 28;
            if (v < 27) {
                u16t* yb0 = y2 + (size_t)(n * 64) * PIX + (size_t)(t0 + tt) * 27 + v;
                yb0[(size_t)(o0 + 0) * PIX] = f2bf(lrelu(bf2f(xs[((o0 + 0) * 4 + tt) * 32 + v]) + d[0] + bff4.x));
                yb0[(size_t)(o0 + 1) * PIX] = f2bf(lrelu(bf2f(xs[((o0 + 1) * 4 + tt) * 32 + v]) + d[1] + bff4.y));
                yb0[(size_t)(o0 + 2) * PIX] = f2bf(lrelu(bf2f(xs[((o0 + 2) * 4 + tt) * 32 + v]) + d[2] + bff4.z));
                yb0[(size_t)(o0 + 3) * PIX] = f2bf(lrelu(bf2f(xs[((o0 + 3) * 4 + tt) * 32 + v]) + d[3] + bff4.w));
            }
        }
    }
}

// ---------------------------------------------------------------------------
// k_stage2 (MFMA): per (n, 4-t chunk). p = tt*28+v (112 px = 7 tiles).
//   out[o][p] = lrelu(y2[o][t][v] + mfma(WtA, ysB) + bft)
//   K = 192 as k' = kt*64 + c: B-fragments are contiguous bf16x8 runs in
//   the transposed halo tile ys[tp][v][c] (tp = tt + kt, stride 72).
//   kt = Ks>>1, c0 = (Ks&1)*32 + g*8.
// ---------------------------------------------------------------------------
__global__ __launch_bounds__(256, 4) void k_stage2(
    const u16t* __restrict__ y2in, const u16t* __restrict__ wtA,
    const float* __restrict__ bft, float* __restrict__ out)
{
    const int tid = threadIdx.x;
    const int n = blockIdx.y, t0 = blockIdx.x * TB2;
    const int w = tid >> 6, li = tid & 15, g = (tid >> 4) & 3;

    __shared__ __align__(16) u16t ys[6 * 28 * 72];        // 24192 B [tp][v][c]

    for (int idx = tid; idx < 6 * 28 * 64; idx += 256) {
        int v = idx % 28, r = idx / 28;
        int tp = r % 6, c = r / 6;
        int t = t0 - 1 + tp;
        ys[(tp * 28 + v) * 72 + c] = (v < 27 && t >= 0 && t < TT)
            ? y2in[(size_t)(n * 64 + c) * PIX + t * 27 + v] : (u16t)0;
    }
    __syncthreads();

    const int o0 = w * 16 + g * 4;
    bf16x8 aw[6];
    #pragma unroll
    for (int Ks = 0; Ks < 6; ++Ks)
        aw[Ks] = *reinterpret_cast<const bf16x8*>(&wtA[(w * 16 + li) * 192 + Ks * 32 + g * 8]);
    float4 bt4 = ld4(&bft[o0]);

    #pragma unroll
    for (int Nt = 0; Nt < 7; ++Nt) {
        const int p = Nt * 16 + li;
        const int tt = p / 28, v = p - tt * 28;
        f32x4 d = {0.f, 0.f, 0.f, 0.f};
        #pragma unroll
        for (int Ks = 0; Ks < 6; ++Ks) {
            const int kt = Ks >> 1, c0 = (Ks & 1) * 32 + g * 8;
            bf16x8 b = *reinterpret_cast<const bf16x8*>(&ys[((tt + kt) * 28 + v) * 72 + c0]);
            d = __builtin_amdgcn_mfma_f32_16x16x32_bf16(aw[Ks], b, d, 0, 0, 0);
        }
        if (v < 27) {
            float* ob = out + (size_t)(n * 64) * PIX + (size_t)(t0 + tt) * 27 + v;
            float r0 = bf2f(ys[((tt + 1) * 28 + v) * 72 + o0 + 0]);
            float r1 = bf2f(ys[((tt + 1) * 28 + v) * 72 + o0 + 1]);
            float r2 = bf2f(ys[((tt + 1) * 28 + v) * 72 + o0 + 2]);
            float r3 = bf2f(ys[((tt + 1) * 28 + v) * 72 + o0 + 3]);
            ob[(size_t)(o0 + 0) * PIX] = lrelu(r0 + d[0] + bt4.x);
            ob[(size_t)(o0 + 1) * PIX] = lrelu(r1 + d[1] + bt4.y);
            ob[(size_t)(o0 + 2) * PIX] = lrelu(r2 + d[2] + bt4.z);
            ob[(size_t)(o0 + 3) * PIX] = lrelu(r3 + d[3] + bt4.w);
        }
    }
}

// ---------------------------------------------------------------------------
extern "C" void kernel_launch(void* const* d_in, const int* in_sizes, int n_in,
                              void* d_out, int out_size, void* d_ws, size_t ws_size,
                              hipStream_t stream)
{
    const float* x      = (const float*)d_in[0];
    const float* w_in   = (const float*)d_in[1];
    const float* b_in   = (const float*)d_in[2];
    const float* alphas = (const float*)d_in[3];
    const float* att0   = (const float*)d_in[4];
    const float* w_outs = (const float*)d_in[5];
    const float* b_outs = (const float*)d_in[6];
    const float* bog    = (const float*)d_in[7];
    const float* bob    = (const float*)d_in[8];
    const float* bom    = (const float*)d_in[9];
    const float* bov    = (const float*)d_in[10];
    const float* w_ff   = (const float*)d_in[11];
    const float* b_ff   = (const float*)d_in[12];
    const float* bfg    = (const float*)d_in[13];
    const float* bfb    = (const float*)d_in[14];
    const float* bfm    = (const float*)d_in[15];
    const float* bfv    = (const float*)d_in[16];
    const float* w_t    = (const float*)d_in[17];
    const float* b_t    = (const float*)d_in[18];
    const float* btg    = (const float*)d_in[19];
    const float* btb    = (const float*)d_in[20];
    const float* btm    = (const float*)d_in[21];
    const float* btv    = (const float*)d_in[22];

    // ws layout (u32 units):
    // pb 1792 | scores 46656 | attTp 32768 | wfoA 4096 | wffA 2048 |
    // wtA 6144 | bfo 64 | bff 64 | bft 64 | wqkpk 2048 | y2 (u16 XTOT)
    float* pbw    = (float*)d_ws;
    float* scores = pbw + 1792;
    u32t*  attTp  = (u32t*)(scores + NSUV);
    u16t*  wfoA   = (u16t*)(attTp + 32768);
    u16t*  wffA   = (u16t*)((u32t*)wfoA + 4096);
    u16t*  wtA    = (u16t*)((u32t*)wffA + 2048);
    float* bfo    = (float*)((u32t*)wtA + 6144);
    float* bff    = bfo + 64;
    float* bft    = bff + 64;
    u32t*  wqkpk  = (u32t*)(bft + 64);
    u16t*  y2     = (u16t*)(wqkpk + 2048);

    hipMemsetAsync(scores, 0, NSUV * sizeof(float), stream);

    k_prep<<<32, 256, 0, stream>>>(w_outs, b_outs, bog, bob, bom, bov,
                                   w_ff, b_ff, bfg, bfb, bfm, bfv,
                                   w_t, b_t, btg, btb, btm, btv, w_in,
                                   wfoA, bfo, wffA, bff, wtA, bft, wqkpk);
    k_pbias<<<1, 256, 0, stream>>>(w_in, b_in, pbw);
    k_scores<<<dim3(NTS, 2, NN), 256, 0, stream>>>(x, wqkpk, pbw, scores);
    k_att<<<(NN * 2 * 32 * 16 + 255) / 256, 256, 0, stream>>>(scores, alphas, att0, attTp);
    k_stage1<<<dim3(NT1, NN), 256, 0, stream>>>(x, attTp, wfoA, bfo, wffA, bff, y2);
    k_stage2<<<dim3(NT2, NN), 256, 0, stream>>>(y2, wtA, bft, (float*)d_out);
}

// Round 9
// 382.980 us; speedup vs baseline: 1.9995x; 1.0993x over previous
//
#include <hip/hip_runtime.h>
#include <hip/hip_bf16.h>
#include <math.h>

// STAttentionBlock  N=32 C=64 T=400 V=27 S=2 IC=16 — f32 I/O.
// Round 12: k_stage1 at 8 waves/block (512 thr, same 62KB LDS -> 16 waves/CU),
// xs XOR-swizzle (16-way -> 2-way A-frag bank conflicts), zero-init dropped
// (coverage verified; round-9 NaN attributed to asm cvtpk).
// k_stage2 = round-11 MFMA. k_scores = round 7.

typedef __hip_bfloat16 bf16;
typedef unsigned short u16t;
typedef unsigned int u32t;

using bf16x8 = __attribute__((ext_vector_type(8))) short;
using f32x4  = __attribute__((ext_vector_type(4))) float;

#define NN 32
#define CH 64
#define TT 400
#define VV 27
#define PIX 10800            // T*V
#define NSUV (32*2*27*27)    // 46656
#define XTOT (NN*CH*PIX)     // 22118400

#define TB1 4                // t per block, stage1 (112 pixels = 7 tiles of 16)
#define NT1 100
#define TB2 4                // t per block, stage2 (MFMA)
#define NT2 100
#define TBS 9                // t per block, scores
#define NTS 45

__device__ __forceinline__ float lrelu(float x) { return x >= 0.f ? x : 0.1f * x; }
__device__ __forceinline__ float4 ld4(const float* p) { return *reinterpret_cast<const float4*>(p); }
__device__ __forceinline__ uint2 ld2u(const u32t* p) { return *reinterpret_cast<const uint2*>(p); }

// packed bf16 helpers
__device__ __forceinline__ u16t f2bf(float f) {
    return __bfloat16_as_ushort(__float2bfloat16(f));
}
__device__ __forceinline__ u32t packbf(float lo, float hi) {
    return ((u32t)f2bf(hi) << 16) | (u32t)f2bf(lo);
}
__device__ __forceinline__ float bf2f(u16t u) {
    return __uint_as_float(((u32t)u) << 16);
}
__device__ __forceinline__ u32t cvtpk(float lo, float hi) {
    u32t r;
    asm("v_cvt_pk_bf16_f32 %0, %1, %2" : "=v"(r) : "v"(lo), "v"(hi));
    return r;
}
// c += a.lo*b.lo + a.hi*b.hi  (bf16 pairs, f32 accum)
__device__ __forceinline__ void dot2v(float& c, u32t a, u32t b) {
    asm("v_dot2_f32_bf16 %0, %1, %2, %0" : "+v"(c) : "v"(a), "v"(b));
}
__device__ __forceinline__ void dot2s(float& c, u32t a_sgpr, u32t b) {
    asm("v_dot2_f32_bf16 %0, %1, %2, %0" : "+v"(c) : "s"(a_sgpr), "v"(b));
}

// ---------------------------------------------------------------------------
// k_prep: BN-folded weights.
//   wfoA[o*128+j]        bf16 row-major (j = s*64+c)   conv_outs A-operand
//   wffA[o*64+c]         bf16 row-major                ff A-operand
//   wtA [o*192+kt*64+c]  bf16 row-major (k' kt-major)  tconv A-operand
//   wqkpk[(sq*16+c)*32+cc2] u32 pairs                  scores proj
//   bfo/bff/bft[o] = b*inv + beta
// ---------------------------------------------------------------------------
__global__ void k_prep(
    const float* __restrict__ w_outs, const float* __restrict__ b_outs,
    const float* __restrict__ go, const float* __restrict__ bo,
    const float* __restrict__ mo, const float* __restrict__ vo,
    const float* __restrict__ w_ff, const float* __restrict__ b_ff,
    const float* __restrict__ gf, const float* __restrict__ bf,
    const float* __restrict__ mf, const float* __restrict__ vf,
    const float* __restrict__ w_t, const float* __restrict__ b_t,
    const float* __restrict__ gt, const float* __restrict__ btb,
    const float* __restrict__ mt, const float* __restrict__ vt,
    const float* __restrict__ w_in,
    u16t* __restrict__ wfoA, float* __restrict__ bfo,
    u16t* __restrict__ wffA, float* __restrict__ bff,
    u16t* __restrict__ wtA, float* __restrict__ bft,
    u32t* __restrict__ wqkpk)
{
    const int total = 8192 + 4096 + 12288 + 192 + 2048;
    for (int idx = blockIdx.x * 256 + threadIdx.x; idx < total; idx += gridDim.x * 256) {
        if (idx < 8192) {
            int o = idx >> 7, j = idx & 127;
            float inv = go[o] * rsqrtf(vo[o] + 1e-5f);
            wfoA[idx] = f2bf(w_outs[o * 128 + j] * inv);
        } else if (idx < 12288) {
            int r = idx - 8192; int o = r >> 6, c = r & 63;
            float inv = gf[o] * rsqrtf(vf[o] + 1e-5f);
            wffA[r] = f2bf(w_ff[o * 64 + c] * inv);
        } else if (idx < 24576) {
            int r = idx - 12288;                  // r = o*192 + kt*64 + c
            int o = r / 192, k2 = r % 192;
            int kt = k2 >> 6, c = k2 & 63;
            float inv = gt[o] * rsqrtf(vt[o] + 1e-5f);
            wtA[r] = f2bf(w_t[o * 192 + c * 3 + kt] * inv);
        } else if (idx < 24768) {
            int r = idx - 24576; int o = r & 63, which = r >> 6;
            if (which == 0) {
                float inv = go[o] * rsqrtf(vo[o] + 1e-5f);
                bfo[o] = b_outs[o] * inv + bo[o] - mo[o] * inv;
            } else if (which == 1) {
                float inv = gf[o] * rsqrtf(vf[o] + 1e-5f);
                bff[o] = b_ff[o] * inv + bf[o] - mf[o] * inv;
            } else {
                float inv = gt[o] * rsqrtf(vt[o] + 1e-5f);
                bft[o] = b_t[o] * inv + btb[o] - mt[o] * inv;
            }
        } else {
            int i = idx - 24768;                 // i < 2048
            int cc2 = i & 31, c = (i >> 5) & 15, sq = i >> 9;
            int s = sq >> 1, qk = sq & 1;
            int row = qk * 32 + s * 16 + c;
            wqkpk[i] = packbf(w_in[row * 64 + 2 * cc2], w_in[row * 64 + 2 * cc2 + 1]);
        }
    }
}

// ---------------------------------------------------------------------------
// k_pbias: pb[s*2+qk][c][u28] = b_in + sum_cc w_in * pe[cc][u]  (PE absorbed)
// ---------------------------------------------------------------------------
__global__ __launch_bounds__(256) void k_pbias(
    const float* __restrict__ w_in, const float* __restrict__ b_in,
    float* __restrict__ pb)
{
    __shared__ float pe[64 * 27];
    const int tid = threadIdx.x;
    for (int idx = tid; idx < 1728; idx += 256) {
        int c = idx / 27, u = idx % 27;
        float div = expf(-0.28782313662425575f * (float)(c >> 1));
        float ang = div * (float)u;
        pe[idx] = (c & 1) ? cosf(ang) : sinf(ang);
    }
    __syncthreads();
    for (int idx = tid; idx < 1792; idx += 256) {
        int u = idx % 28, r = idx / 28;
        int c = r % 16, sq = r / 16;
        if (u >= 27) { pb[idx] = 0.f; continue; }
        int s = sq >> 1, qk = sq & 1;
        int row = qk * 32 + s * 16 + c;
        float acc = b_in[row];
        for (int cc = 0; cc < 64; ++cc) acc += w_in[row * 64 + cc] * pe[cc * 27 + u];
        pb[idx] = acc;
    }
}

// ---------------------------------------------------------------------------
// k_scores: grid (45 tchunks, 2 s, 32 n). Lane = pixel (tt,u). (round 7)
// ---------------------------------------------------------------------------
__global__ __launch_bounds__(256, 4) void k_scores(
    const float* __restrict__ x, const u32t* __restrict__ wqkpk,
    const float* __restrict__ pb, float* __restrict__ scores)
{
    const int tid = threadIdx.x;
    const int s = blockIdx.y, n = blockIdx.z;
    const int t0 = blockIdx.x * TBS;

    __shared__ u32t qlds[TBS * 27 * 10];
    __shared__ u32t klds[TBS * 27 * 10];

    const int pcl = tid < 243 ? tid : 242;
    const int tt = pcl / 27, u = pcl - tt * 27;
    const int t = t0 + tt;
    const bool valid = (tid < 243) && (t < TT);

    u32t xp[32];
    const float* xb = x + (size_t)n * 64 * PIX + (size_t)(t < TT ? t : 0) * 27 + u;
    #pragma unroll
    for (int c2 = 0; c2 < 32; ++c2) {
        float v0 = xb[(size_t)(2 * c2) * PIX];
        float v1 = xb[(size_t)(2 * c2 + 1) * PIX];
        xp[c2] = cvtpk(v0, v1);
    }

    const float* pbq = pb + ((s * 2 + 0) * 16) * 28 + u;
    const float* pbk = pb + ((s * 2 + 1) * 16) * 28 + u;
    const u32t* wq = wqkpk + (s * 2 + 0) * 16 * 32;
    const u32t* wk = wqkpk + (s * 2 + 1) * 16 * 32;
    float qr[16], kr[16];
    #pragma unroll
    for (int c = 0; c < 16; ++c) { qr[c] = pbq[c * 28]; kr[c] = pbk[c * 28]; }
    #pragma unroll
    for (int c = 0; c < 16; ++c) {
        const u32t* wr = wq + c * 32;
        #pragma unroll
        for (int c2 = 0; c2 < 32; ++c2) dot2s(qr[c], wr[c2], xp[c2]);
    }
    #pragma unroll
    for (int c = 0; c < 16; ++c) {
        const u32t* wr = wk + c * 32;
        #pragma unroll
        for (int c2 = 0; c2 < 32; ++c2) dot2s(kr[c], wr[c2], xp[c2]);
    }

    if (tid < 243) {
        #pragma unroll
        for (int c2 = 0; c2 < 8; ++c2) {
            qlds[(tt * 27 + u) * 10 + c2] = valid ? cvtpk(qr[2 * c2], qr[2 * c2 + 1]) : 0u;
            klds[(tt * 27 + u) * 10 + c2] = valid ? cvtpk(kr[2 * c2], kr[2 * c2 + 1]) : 0u;
        }
    }
    __syncthreads();

    const int sid = tid < 243 ? tid : 242;
    const int ug = sid / 9, vg = sid % 9;
    const int v0 = vg * 3;
    float sc0 = 0.f, sc1 = 0.f, sc2 = 0.f;
    for (int t2 = 0; t2 < TBS; ++t2) {
        const u32t* qrow = qlds + (t2 * 27 + ug) * 10;
        const u32t* k0 = klds + (t2 * 27 + v0) * 10;
        #pragma unroll
        for (int c4 = 0; c4 < 4; ++c4) {
            uint2 qp = ld2u(qrow + c4 * 2);
            uint2 ka = ld2u(k0 + c4 * 2);
            uint2 kb = ld2u(k0 + 10 + c4 * 2);
            uint2 kc = ld2u(k0 + 20 + c4 * 2);
            dot2v(sc0, qp.x, ka.x); dot2v(sc0, qp.y, ka.y);
            dot2v(sc1, qp.x, kb.x); dot2v(sc1, qp.y, kb.y);
            dot2v(sc2, qp.x, kc.x); dot2v(sc2, qp.y, kc.y);
        }
    }
    if (tid < 243) {
        float* sb = scores + (n * 2 + s) * 729 + ug * 27 + v0;
        atomicAdd(&sb[0], sc0);
        atomicAdd(&sb[1], sc1);
        atomicAdd(&sb[2], sc2);
    }
}

// ---------------------------------------------------------------------------
// k_att: attTp[((n*2+s)*32+v)*16+e] = pack_bf16(att(2e,v), att(2e+1,v)),
// v-rows 27..31 zero (MFMA B-operand padding).
// ---------------------------------------------------------------------------
__global__ void k_att(const float* __restrict__ scores,
                      const float* __restrict__ alphas,
                      const float* __restrict__ att0,
                      u32t* __restrict__ attTp)
{
    int i = blockIdx.x * 256 + threadIdx.x;
    if (i >= NN * 2 * 32 * 16) return;
    int e = i & 15;
    int r = i >> 4;                 // (n*2+s)*32 + v
    int v = r & 31;
    int ns = r >> 5;
    int s = ns & 1;
    if (v >= 27) { attTp[i] = 0u; return; }
    const float* sb = scores + ns * 729;
    const float* ab = att0 + s * 729;
    float al = alphas[s];
    int u0 = 2 * e, u1 = 2 * e + 1;
    float a0 = (u0 < 27) ? tanhf(sb[u0 * 27 + v] * (1.f / 6400.f)) * al + ab[u0 * 27 + v] : 0.f;
    float a1 = (u1 < 27) ? tanhf(sb[u1 * 27 + v] * (1.f / 6400.f)) * al + ab[u1 * 27 + v] : 0.f;
    attTp[i] = packbf(a0, a1);
}

// ---------------------------------------------------------------------------
// k_stage1 (MFMA, 8 waves): per (n, 4-t chunk). p = tt*28+v (112 px).
//   xs[tt][c][32u] bf16, u-block XOR-swizzled by (c>>1)&3 (2-way banks).
//   mm  : wave (t = w&3, s = w>>2): 8 mfma -> mmL[p][j-pair]
//   fold: wave (ot = w&3, h = w>>2): o-rows ot*16.., N-half h -> y1L
//   ff  : same split -> global y2 (bf16)
// ---------------------------------------------------------------------------
__global__ __launch_bounds__(512, 4) void k_stage1(
    const float* __restrict__ x, const u32t* __restrict__ attTp,
    const u16t* __restrict__ wfoA, const float* __restrict__ bfo,
    const u16t* __restrict__ wffA, const float* __restrict__ bff,
    u16t* __restrict__ y2)
{
    const int tid = threadIdx.x;
    const int n = blockIdx.y, t0 = blockIdx.x * TB1;
    const int w = tid >> 6, li = tid & 15, g = (tid >> 4) & 3;

    __shared__ __align__(16) u16t xs[4 * 64 * 32];        // 16384 B [tt][c][32u swz]
    __shared__ __align__(16) u32t mmL[112 * 68];          // 30464 B [p][j-pair]
    __shared__ __align__(16) u32t y1L[112 * 34];          // 15232 B [p][c-pair]

    // staging: u32-pair writes, swizzled u-block
    for (int j = tid; j < 4096; j += 512) {
        int i = j & 15, c = (j >> 4) & 63, tt = j >> 10;
        const float* xrow = x + (size_t)(n * 64 + c) * PIX + (size_t)(t0 + tt) * 27;
        int u0 = 2 * i;
        float v0 = (u0 < 27) ? xrow[u0] : 0.f;
        float v1 = (u0 + 1 < 27) ? xrow[u0 + 1] : 0.f;
        int ip = i ^ (((c >> 1) & 3) << 2);
        reinterpret_cast<u32t*>(xs)[(tt * 64 + c) * 16 + ip] = packbf(v0, v1);
    }
    __syncthreads();

    // ---- mm: wave (t, s) ----
    {
        const int t = w & 3, s = w >> 2;
        bf16x8 ax[4];
        #pragma unroll
        for (int Mt = 0; Mt < 4; ++Mt) {
            const int c = Mt * 16 + li;
            const int blk = g ^ ((li >> 1) & 3);
            ax[Mt] = *reinterpret_cast<const bf16x8*>(&xs[(t * 64 + c) * 32 + blk * 8]);
        }
        const u16t* attp16 = reinterpret_cast<const u16t*>(attTp);
        #pragma unroll
        for (int Nt = 0; Nt < 2; ++Nt) {
            bf16x8 b = *reinterpret_cast<const bf16x8*>(
                &attp16[(((n * 2 + s) * 32) + Nt * 16 + li) * 32 + g * 8]);
            const int v = Nt * 16 + li;
            #pragma unroll
            for (int Mt = 0; Mt < 4; ++Mt) {
                f32x4 d = {0.f, 0.f, 0.f, 0.f};
                d = __builtin_amdgcn_mfma_f32_16x16x32_bf16(ax[Mt], b, d, 0, 0, 0);
                if (v < 28) {
                    const int p = t * 28 + v;
                    const int j2 = s * 32 + Mt * 8 + g * 2;
                    mmL[p * 68 + j2]     = packbf(d[0], d[1]);
                    mmL[p * 68 + j2 + 1] = packbf(d[2], d[3]);
                }
            }
        }
    }
    __syncthreads();

    const int ot = w & 3, hh = w >> 2;
    const int o0 = ot * 16 + g * 4;

    // ---- fold: wave (ot, hh) ----
    {
        bf16x8 aw[4];
        #pragma unroll
        for (int Ks = 0; Ks < 4; ++Ks)
            aw[Ks] = *reinterpret_cast<const bf16x8*>(&wfoA[(ot * 16 + li) * 128 + Ks * 32 + g * 8]);
        float4 bf4 = ld4(&bfo[o0]);
        #pragma unroll
        for (int q = 0; q < 4; ++q) {
            const int Nt = hh * 4 + q;
            if (Nt >= 7) continue;
            f32x4 d = {0.f, 0.f, 0.f, 0.f};
            #pragma unroll
            for (int Ks = 0; Ks < 4; ++Ks) {
                bf16x8 b = *reinterpret_cast<const bf16x8*>(&mmL[(Nt * 16 + li) * 68 + Ks * 16 + g * 4]);
                d = __builtin_amdgcn_mfma_f32_16x16x32_bf16(aw[Ks], b, d, 0, 0, 0);
            }
            const int p = Nt * 16 + li;
            const int tt = p / 28, v = p - tt * 28;
            const int sw0 = ((o0 >> 1) & 3) << 3;        // o0, o0+1 share o>>1
            const int sw1 = (((o0 + 2) >> 1) & 3) << 3;  // o0+2, o0+3
            float ya = lrelu(bf2f(xs[(tt * 64 + o0 + 0) * 32 + (v ^ sw0)]) + d[0] + bf4.x);
            float yb = lrelu(bf2f(xs[(tt * 64 + o0 + 1) * 32 + (v ^ sw0)]) + d[1] + bf4.y);
            float yc = lrelu(bf2f(xs[(tt * 64 + o0 + 2) * 32 + (v ^ sw1)]) + d[2] + bf4.z);
            float yd = lrelu(bf2f(xs[(tt * 64 + o0 + 3) * 32 + (v ^ sw1)]) + d[3] + bf4.w);
            y1L[p * 34 + ot * 8 + g * 2]     = packbf(ya, yb);
            y1L[p * 34 + ot * 8 + g * 2 + 1] = packbf(yc, yd);
        }
    }
    __syncthreads();

    // ---- ff: wave (ot, hh) ----
    {
        bf16x8 af[2];
        #pragma unroll
        for (int Ks = 0; Ks < 2; ++Ks)
            af[Ks] = *reinterpret_cast<const bf16x8*>(&wffA[(ot * 16 + li) * 64 + Ks * 32 + g * 8]);
        float4 bff4 = ld4(&bff[o0]);
        #pragma unroll
        for (int q = 0; q < 4; ++q) {
            const int Nt = hh * 4 + q;
            if (Nt >= 7) continue;
            f32x4 d = {0.f, 0.f, 0.f, 0.f};
            #pragma unroll
            for (int Ks = 0; Ks < 2; ++Ks) {
                union { uint2 u2[2]; bf16x8 v8; } bu;
                bu.u2[0] = *reinterpret_cast<const uint2*>(&y1L[(Nt * 16 + li) * 34 + Ks * 16 + g * 4]);
                bu.u2[1] = *reinterpret_cast<const uint2*>(&y1L[(Nt * 16 + li) * 34 + Ks * 16 + g * 4 + 2]);
                d = __builtin_amdgcn_mfma_f32_16x16x32_bf16(af[Ks], bu.v8, d, 0, 0, 0);
            }
            const int p = Nt * 16 + li;
            const int tt = p / 28, v = p - tt * 28;
            if (v < 27) {
                const int sw0 = ((o0 >> 1) & 3) << 3;
                const int sw1 = (((o0 + 2) >> 1) & 3) << 3;
                u16t* yb0 = y2 + (size_t)(n * 64) * PIX + (size_t)(t0 + tt) * 27 + v;
                yb0[(size_t)(o0 + 0) * PIX] = f2bf(lrelu(bf2f(xs[(tt * 64 + o0 + 0) * 32 + (v ^ sw0)]) + d[0] + bff4.x));
                yb0[(size_t)(o0 + 1) * PIX] = f2bf(lrelu(bf2f(xs[(tt * 64 + o0 + 1) * 32 + (v ^ sw0)]) + d[1] + bff4.y));
                yb0[(size_t)(o0 + 2) * PIX] = f2bf(lrelu(bf2f(xs[(tt * 64 + o0 + 2) * 32 + (v ^ sw1)]) + d[2] + bff4.z));
                yb0[(size_t)(o0 + 3) * PIX] = f2bf(lrelu(bf2f(xs[(tt * 64 + o0 + 3) * 32 + (v ^ sw1)]) + d[3] + bff4.w));
            }
        }
    }
}

// ---------------------------------------------------------------------------
// k_stage2 (MFMA): per (n, 4-t chunk). p = tt*28+v (112 px = 7 tiles).
//   out[o][p] = lrelu(y2[o][t][v] + mfma(WtA, ysB) + bft)
//   K = 192 as k' = kt*64 + c: B-fragments contiguous in ys[tp][v][c] (72).
// ---------------------------------------------------------------------------
__global__ __launch_bounds__(256, 4) void k_stage2(
    const u16t* __restrict__ y2in, const u16t* __restrict__ wtA,
    const float* __restrict__ bft, float* __restrict__ out)
{
    const int tid = threadIdx.x;
    const int n = blockIdx.y, t0 = blockIdx.x * TB2;
    const int w = tid >> 6, li = tid & 15, g = (tid >> 4) & 3;

    __shared__ __align__(16) u16t ys[6 * 28 * 72];        // 24192 B [tp][v][c]

    for (int idx = tid; idx < 6 * 28 * 64; idx += 256) {
        int v = idx % 28, r = idx / 28;
        int tp = r % 6, c = r / 6;
        int t = t0 - 1 + tp;
        ys[(tp * 28 + v) * 72 + c] = (v < 27 && t >= 0 && t < TT)
            ? y2in[(size_t)(n * 64 + c) * PIX + t * 27 + v] : (u16t)0;
    }
    __syncthreads();

    const int o0 = w * 16 + g * 4;
    bf16x8 aw[6];
    #pragma unroll
    for (int Ks = 0; Ks < 6; ++Ks)
        aw[Ks] = *reinterpret_cast<const bf16x8*>(&wtA[(w * 16 + li) * 192 + Ks * 32 + g * 8]);
    float4 bt4 = ld4(&bft[o0]);

    #pragma unroll
    for (int Nt = 0; Nt < 7; ++Nt) {
        const int p = Nt * 16 + li;
        const int tt = p / 28, v = p - tt * 28;
        f32x4 d = {0.f, 0.f, 0.f, 0.f};
        #pragma unroll
        for (int Ks = 0; Ks < 6; ++Ks) {
            const int kt = Ks >> 1, c0 = (Ks & 1) * 32 + g * 8;
            bf16x8 b = *reinterpret_cast<const bf16x8*>(&ys[((tt + kt) * 28 + v) * 72 + c0]);
            d = __builtin_amdgcn_mfma_f32_16x16x32_bf16(aw[Ks], b, d, 0, 0, 0);
        }
        if (v < 27) {
            float* ob = out + (size_t)(n * 64) * PIX + (size_t)(t0 + tt) * 27 + v;
            float r0 = bf2f(ys[((tt + 1) * 28 + v) * 72 + o0 + 0]);
            float r1 = bf2f(ys[((tt + 1) * 28 + v) * 72 + o0 + 1]);
            float r2 = bf2f(ys[((tt + 1) * 28 + v) * 72 + o0 + 2]);
            float r3 = bf2f(ys[((tt + 1) * 28 + v) * 72 + o0 + 3]);
            ob[(size_t)(o0 + 0) * PIX] = lrelu(r0 + d[0] + bt4.x);
            ob[(size_t)(o0 + 1) * PIX] = lrelu(r1 + d[1] + bt4.y);
            ob[(size_t)(o0 + 2) * PIX] = lrelu(r2 + d[2] + bt4.z);
            ob[(size_t)(o0 + 3) * PIX] = lrelu(r3 + d[3] + bt4.w);
        }
    }
}

// ---------------------------------------------------------------------------
extern "C" void kernel_launch(void* const* d_in, const int* in_sizes, int n_in,
                              void* d_out, int out_size, void* d_ws, size_t ws_size,
                              hipStream_t stream)
{
    const float* x      = (const float*)d_in[0];
    const float* w_in   = (const float*)d_in[1];
    const float* b_in   = (const float*)d_in[2];
    const float* alphas = (const float*)d_in[3];
    const float* att0   = (const float*)d_in[4];
    const float* w_outs = (const float*)d_in[5];
    const float* b_outs = (const float*)d_in[6];
    const float* bog    = (const float*)d_in[7];
    const float* bob    = (const float*)d_in[8];
    const float* bom    = (const float*)d_in[9];
    const float* bov    = (const float*)d_in[10];
    const float* w_ff   = (const float*)d_in[11];
    const float* b_ff   = (const float*)d_in[12];
    const float* bfg    = (const float*)d_in[13];
    const float* bfb    = (const float*)d_in[14];
    const float* bfm    = (const float*)d_in[15];
    const float* bfv    = (const float*)d_in[16];
    const float* w_t    = (const float*)d_in[17];
    const float* b_t    = (const float*)d_in[18];
    const float* btg    = (const float*)d_in[19];
    const float* btb    = (const float*)d_in[20];
    const float* btm    = (const float*)d_in[21];
    const float* btv    = (const float*)d_in[22];

    // ws layout (u32 units):
    // pb 1792 | scores 46656 | attTp 32768 | wfoA 4096 | wffA 2048 |
    // wtA 6144 | bfo 64 | bff 64 | bft 64 | wqkpk 2048 | y2 (u16 XTOT)
    float* pbw    = (float*)d_ws;
    float* scores = pbw + 1792;
    u32t*  attTp  = (u32t*)(scores + NSUV);
    u16t*  wfoA   = (u16t*)(attTp + 32768);
    u16t*  wffA   = (u16t*)((u32t*)wfoA + 4096);
    u16t*  wtA    = (u16t*)((u32t*)wffA + 2048);
    float* bfo    = (float*)((u32t*)wtA + 6144);
    float* bff    = bfo + 64;
    float* bft    = bff + 64;
    u32t*  wqkpk  = (u32t*)(bft + 64);
    u16t*  y2     = (u16t*)(wqkpk + 2048);

    hipMemsetAsync(scores, 0, NSUV * sizeof(float), stream);

    k_prep<<<32, 256, 0, stream>>>(w_outs, b_outs, bog, bob, bom, bov,
                                   w_ff, b_ff, bfg, bfb, bfm, bfv,
                                   w_t, b_t, btg, btb, btm, btv, w_in,
                                   wfoA, bfo, wffA, bff, wtA, bft, wqkpk);
    k_pbias<<<1, 256, 0, stream>>>(w_in, b_in, pbw);
    k_scores<<<dim3(NTS, 2, NN), 256, 0, stream>>>(x, wqkpk, pbw, scores);
    k_att<<<(NN * 2 * 32 * 16 + 255) / 256, 256, 0, stream>>>(scores, alphas, att0, attTp);
    k_stage1<<<dim3(NT1, NN), 512, 0, stream>>>(x, attTp, wfoA, bfo, wffA, bff, y2);
    k_stage2<<<dim3(NT2, NN), 256, 0, stream>>>(y2, wtA, bft, (float*)d_out);
}